// Round 15
// baseline (356.120 us; speedup 1.0000x reference)
//
#include <hip/hip_runtime.h>

#define N 1024
#define NE 32768
#define S 4
#define STEPS 31
#define FEAT (S * STEPS)  // 124
#define PLANE ((size_t)S * N * N)   // 4 Mi elements (8 MB as ushort)
#define MAXT 192

typedef short short8 __attribute__((ext_vector_type(8)));
typedef short short4v __attribute__((ext_vector_type(4)));
typedef float f32x4 __attribute__((ext_vector_type(4)));

// ---- bf16 helpers (RNE) ---------------------------------------------------
__device__ __forceinline__ ushort f2bf(float x) {
    union { float f; unsigned u; } v; v.f = x;
    unsigned r = v.u + 0x7fffu + ((v.u >> 16) & 1u);
    return (ushort)(r >> 16);
}
__device__ __forceinline__ float bf2f(ushort h) {
    union { unsigned u; float f; } v; v.u = ((unsigned)h) << 16;
    return v.f;
}

__device__ __forceinline__ void gload16(const ushort* g, ushort* l) {
    __builtin_amdgcn_global_load_lds(
        (const __attribute__((address_space(1))) unsigned int*)g,
        (__attribute__((address_space(3))) unsigned int*)l, 16, 0, 0);
}

// ---------------------------------------------------------------------------
// Kernel: build P (split bf16 hi/lo), row-major [s][i][j].
// ---------------------------------------------------------------------------
__global__ __launch_bounds__(256) void build_P(const float* __restrict__ coords,
                                               const float* __restrict__ log_sigmas,
                                               ushort* __restrict__ Oh,
                                               ushort* __restrict__ Ol)
{
    const int i   = blockIdx.x;
    const int tid = threadIdx.x;

    float sg[S];
#pragma unroll
    for (int s = 0; s < S; ++s) sg[s] = expf(log_sigmas[s]);
#define CSWP(a, b) { float lo = fminf(sg[a], sg[b]); float hi = fmaxf(sg[a], sg[b]); sg[a] = lo; sg[b] = hi; }
    CSWP(0, 1) CSWP(2, 3) CSWP(0, 2) CSWP(1, 3) CSWP(1, 2)
#undef CSWP
    float inv2s2[S];
#pragma unroll
    for (int s = 0; s < S; ++s) inv2s2[s] = 1.0f / (2.0f * sg[s] * sg[s]);

    const float cx = coords[3 * i + 0];
    const float cy = coords[3 * i + 1];
    const float cz = coords[3 * i + 2];

    float w[4][S];
    float part[S] = {0.f, 0.f, 0.f, 0.f};
#pragma unroll
    for (int c = 0; c < 4; ++c) {
        const int j = tid + c * 256;
        const float dx = cx - coords[3 * j + 0];
        const float dy = cy - coords[3 * j + 1];
        const float dz = cz - coords[3 * j + 2];
        const float d2 = dx * dx + dy * dy + dz * dz;
#pragma unroll
        for (int s = 0; s < S; ++s) {
            const float v = (j == i) ? 0.0f : expf(-d2 * inv2s2[s]);
            w[c][s] = v;
            part[s] += v;
        }
    }

    __shared__ float red[S][256];
#pragma unroll
    for (int s = 0; s < S; ++s) red[s][tid] = part[s];
    __syncthreads();
    for (int st = 128; st > 0; st >>= 1) {
        if (tid < st) {
#pragma unroll
            for (int s = 0; s < S; ++s) red[s][tid] += red[s][tid + st];
        }
        __syncthreads();
    }

    float invden[S];
#pragma unroll
    for (int s = 0; s < S; ++s) invden[s] = 1.0f / fmaxf(red[s][0], 1e-12f);

#pragma unroll
    for (int c = 0; c < 4; ++c) {
        const int j = tid + c * 256;
#pragma unroll
        for (int s = 0; s < S; ++s) {
            const float p = w[c][s] * invden[s];
            const size_t off = ((size_t)s * N + i) * N + j;
            const ushort h = f2bf(p);
            Oh[off] = h;
            Ol[off] = f2bf(p - bf2f(h));
        }
    }
}

// ---------------------------------------------------------------------------
// Kernel: transpose hi/lo pair (used once, for BT1).
// ---------------------------------------------------------------------------
__global__ __launch_bounds__(256) void transpose_hl(const ushort* __restrict__ Xh,
                                                    const ushort* __restrict__ Xl,
                                                    ushort* __restrict__ Yh,
                                                    ushort* __restrict__ Yl)
{
    __shared__ float tile[64][65];
    const size_t zb = (size_t)blockIdx.z * N * N;
    const int tr = blockIdx.y * 64, tc = blockIdx.x * 64;
    const int tid = threadIdx.x;
    const int c  = tid & 63;
    const int r0 = tid >> 6;
#pragma unroll
    for (int i = 0; i < 16; ++i) {
        const int r = r0 + i * 4;
        const size_t idx = zb + (size_t)(tr + r) * N + tc + c;
        tile[r][c] = bf2f(Xh[idx]) + bf2f(Xl[idx]);
    }
    __syncthreads();
#pragma unroll
    for (int i = 0; i < 16; ++i) {
        const int r = r0 + i * 4;
        const size_t idx = zb + (size_t)(tc + r) * N + tr + c;
        const float x = tile[c][r];
        const ushort h = f2bf(x);
        Yh[idx] = h;
        if (Yl) Yl[idx] = f2bf(x - bf2f(h));
    }
}

// ---------------------------------------------------------------------------
// GEMM body (proven round-10..14 schedule): 128x128 tile, BK=32, 8 waves,
// 32x64 wave slice, quad-buffered LDS, depth-2 counted-vmcnt prefetch, one
// barrier per K-step, setprio around MFMA cluster.
// SPLIT=1: C = (Ah+Al)@B, B=(BTh+BTl)^T, 3 MFMA passes.
// SPLIT=0: C = Ah@BTh^T, 1 pass.
// All outputs nullable: Ch/Cl row-major; CTh/CTl transposed.
// `id` = linear block index within this op (0..255), id&7 = row-panel.
// ---------------------------------------------------------------------------
template <bool SPLIT>
__device__ __forceinline__ void gemm_body(const ushort* __restrict__ Ah,
                                          const ushort* __restrict__ Al,
                                          const ushort* __restrict__ BTh,
                                          const ushort* __restrict__ BTl,
                                          ushort* __restrict__ Ch,
                                          ushort* __restrict__ Cl,
                                          ushort* __restrict__ CTh,
                                          ushort* __restrict__ CTl,
                                          int id)
{
    constexpr int NP = SPLIT ? 4 : 2;           // LDS parts
    __shared__ ushort smem[4][NP][128 * 32];    // 128 KB (split) / 64 KB
    const int tid  = threadIdx.x;
    const int w    = tid >> 6;                  // wave 0..7
    const int lane = tid & 63;
    const int wr   = w >> 1;                    // wave row-block 0..3
    const int wc   = w & 1;                     // wave col-block 0..1

    const int yrow = id & 7;
    const int rest = id >> 3;
    const int xcol = rest & 7;
    const int z    = rest >> 3;
    const size_t zb = (size_t)z * N * N;
    const int tr = yrow * 128;
    const int tc = xcol * 128;

    const ushort* gA0 = Ah  + zb + (size_t)tr * N;
    const ushort* gA1 = SPLIT ? (Al  + zb + (size_t)tr * N) : nullptr;
    const ushort* gB0 = BTh + zb + (size_t)tc * N;
    const ushort* gB1 = SPLIT ? (BTl + zb + (size_t)tc * N) : nullptr;

    f32x4 acc[2][4] = {};                       // wave's 32x64 slice

    auto STAGE = [&](int bufi, int k0) __attribute__((always_inline)) {
        const int row = tid >> 2;               // 0..127
        const int kg  = (tid & 3) ^ ((row >> 1) & 3);
        const size_t go = (size_t)row * N + k0 + kg * 8;
        const int lb = w * 512;                 // wave-uniform LDS base (elems)
        gload16(gA0 + go, &smem[bufi][0][lb]);
        if constexpr (SPLIT) {
            gload16(gA1 + go, &smem[bufi][1][lb]);
            gload16(gB0 + go, &smem[bufi][2][lb]);
            gload16(gB1 + go, &smem[bufi][3][lb]);
        } else {
            gload16(gB0 + go, &smem[bufi][1][lb]);
        }
    };

    const int lrow = lane & 15;
    const int lkg  = lane >> 4;

    auto COMPUTE = [&](int bufi) __attribute__((always_inline)) {
        short8 ah[2], al[2], bh[4], bl[4];
#pragma unroll
        for (int m = 0; m < 2; ++m) {
            const int arow = wr * 32 + m * 16 + lrow;
            const int aoff = arow * 32 + ((lkg ^ ((arow >> 1) & 3)) << 3);
            ah[m] = *(const short8*)&smem[bufi][0][aoff];
            if constexpr (SPLIT) al[m] = *(const short8*)&smem[bufi][1][aoff];
        }
#pragma unroll
        for (int n = 0; n < 4; ++n) {
            const int brow = wc * 64 + n * 16 + lrow;
            const int boff = brow * 32 + ((lkg ^ ((brow >> 1) & 3)) << 3);
            if constexpr (SPLIT) {
                bh[n] = *(const short8*)&smem[bufi][2][boff];
                bl[n] = *(const short8*)&smem[bufi][3][boff];
            } else {
                bh[n] = *(const short8*)&smem[bufi][1][boff];
            }
        }
        __builtin_amdgcn_s_setprio(1);
#pragma unroll
        for (int m = 0; m < 2; ++m)
#pragma unroll
            for (int n = 0; n < 4; ++n) {
                acc[m][n] = __builtin_amdgcn_mfma_f32_16x16x32_bf16(ah[m], bh[n], acc[m][n], 0, 0, 0);
                if constexpr (SPLIT) {
                    acc[m][n] = __builtin_amdgcn_mfma_f32_16x16x32_bf16(ah[m], bl[n], acc[m][n], 0, 0, 0);
                    acc[m][n] = __builtin_amdgcn_mfma_f32_16x16x32_bf16(al[m], bh[n], acc[m][n], 0, 0, 0);
                }
            }
        __builtin_amdgcn_s_setprio(0);
    };

    STAGE(0, 0);
    STAGE(1, 32);
#pragma unroll 1
    for (int t = 0; t < 32; ++t) {
        __builtin_amdgcn_sched_barrier(0);
        if (t < 30) {
            STAGE((t + 2) & 3, (t + 2) * 32);
            if constexpr (SPLIT) asm volatile("s_waitcnt vmcnt(8)" ::: "memory");
            else                 asm volatile("s_waitcnt vmcnt(4)" ::: "memory");
        } else if (t == 30) {
            if constexpr (SPLIT) asm volatile("s_waitcnt vmcnt(4)" ::: "memory");
            else                 asm volatile("s_waitcnt vmcnt(2)" ::: "memory");
        } else {
            asm volatile("s_waitcnt vmcnt(0)" ::: "memory");
        }
        __builtin_amdgcn_s_barrier();                 // tile t visible to all
        __builtin_amdgcn_sched_barrier(0);
        COMPUTE(t & 3);
        __builtin_amdgcn_sched_barrier(0);
    }

    // epilogue
#pragma unroll
    for (int m = 0; m < 2; ++m)
#pragma unroll
    for (int n = 0; n < 4; ++n) {
        const f32x4 v = acc[m][n];
        ushort hs[4], ls[4];
#pragma unroll
        for (int r = 0; r < 4; ++r) {
            const float x = v[r];
            hs[r] = f2bf(x);
            ls[r] = f2bf(x - bf2f(hs[r]));
        }
        const int row0 = tr + wr * 32 + m * 16 + lkg * 4;
        const int col  = tc + wc * 64 + n * 16 + lrow;
        if (Ch) {
#pragma unroll
            for (int r = 0; r < 4; ++r) {
                const size_t idx = zb + (size_t)(row0 + r) * N + col;
                Ch[idx] = hs[r];
                if (Cl) Cl[idx] = ls[r];
            }
        }
        if (CTh) {
            short4v hv;
            hv[0] = (short)hs[0]; hv[1] = (short)hs[1];
            hv[2] = (short)hs[2]; hv[3] = (short)hs[3];
            *(short4v*)&CTh[zb + (size_t)col * N + row0] = hv;
            if (CTl) {
                short4v lv;
                lv[0] = (short)ls[0]; lv[1] = (short)ls[1];
                lv[2] = (short)ls[2]; lv[3] = (short)ls[3];
                *(short4v*)&CTl[zb + (size_t)col * N + row0] = lv;
            }
        }
    }
}

template <bool SPLIT>
__global__ __launch_bounds__(512) void gemm_tile(const ushort* __restrict__ Ah,
                                                 const ushort* __restrict__ Al,
                                                 const ushort* __restrict__ BTh,
                                                 const ushort* __restrict__ BTl,
                                                 ushort* __restrict__ Ch,
                                                 ushort* __restrict__ Cl,
                                                 ushort* __restrict__ CTh,
                                                 ushort* __restrict__ CTl)
{
    gemm_body<SPLIT>(Ah, Al, BTh, BTl, Ch, Cl, CTh, CTl, blockIdx.x);
}

// Batched hi-only leaf GEMMs: up to 4 ops in one dispatch (grid = 256*nops).
__global__ __launch_bounds__(512) void gemm_leaf(
    const ushort* A0, const ushort* B0, ushort* C0, ushort* T0,
    const ushort* A1, const ushort* B1, ushort* C1, ushort* T1,
    const ushort* A2, const ushort* B2, ushort* C2, ushort* T2,
    const ushort* A3, const ushort* B3, ushort* C3, ushort* T3)
{
    const int op = blockIdx.x >> 8;
    const int id = blockIdx.x & 255;
    const ushort* A; const ushort* B; ushort* C; ushort* T;
    if      (op == 0) { A = A0; B = B0; C = C0; T = T0; }
    else if (op == 1) { A = A1; B = B1; C = C1; T = T1; }
    else if (op == 2) { A = A2; B = B2; C = C2; T = T2; }
    else              { A = A3; B = B3; C = C3; T = T3; }
    gemm_body<false>(A, nullptr, B, nullptr, C, nullptr, T, nullptr, id);
}

// ---------------------------------------------------------------------------
// Kernel: gather diag + edges (fallback path only).
// ---------------------------------------------------------------------------
__global__ __launch_bounds__(256) void gather_hl(const ushort* __restrict__ Ph,
                                                 const ushort* __restrict__ Pl,
                                                 const int* __restrict__ eidx,
                                                 float* __restrict__ out,
                                                 int t)
{
    const int tid = blockIdx.x * blockDim.x + threadIdx.x;
    const int ND = S * N;
    if (tid < ND) {
        const int s = tid >> 10;
        const int n = tid & (N - 1);
        const size_t off = ((size_t)s * N + n) * N + n;
        float v = bf2f(Ph[off]);
        if (Pl) v += bf2f(Pl[off]);
        out[(size_t)n * FEAT + s * STEPS + t] = v;
    } else {
        const int idx = tid - ND;
        if (idx >= S * NE) return;
        const int s = idx >> 15;
        const int e = idx & (NE - 1);
        const int i = eidx[e];
        const int j = eidx[NE + e];
        const size_t off = ((size_t)s * N + i) * N + j;
        float v = bf2f(Ph[off]);
        if (Pl) v += bf2f(Pl[off]);
        out[(size_t)N * FEAT + (size_t)e * FEAT + s * STEPS + t] = v;
    }
}

// ---------------------------------------------------------------------------
// Bucketing (counting sort of edges by destination column j = eidx[NE+e]).
// ---------------------------------------------------------------------------
__global__ __launch_bounds__(256) void zero_aux(int* __restrict__ p, int n)
{
    for (int i = blockIdx.x * 256 + threadIdx.x; i < n; i += gridDim.x * 256) p[i] = 0;
}

__global__ __launch_bounds__(256) void edge_hist(const int* __restrict__ eidx,
                                                 int* __restrict__ hist)
{
    const int e = blockIdx.x * 256 + threadIdx.x;
    if (e < NE) atomicAdd(&hist[eidx[NE + e]], 1);
}

__global__ __launch_bounds__(1024) void scan1024(const int* __restrict__ hist,
                                                 int* __restrict__ offs)
{
    __shared__ int tmp[1024];
    const int t = threadIdx.x;
    tmp[t] = hist[t];
    __syncthreads();
    for (int d = 1; d < 1024; d <<= 1) {
        int v = (t >= d) ? tmp[t - d] : 0;
        __syncthreads();
        tmp[t] += v;
        __syncthreads();
    }
    offs[t + 1] = tmp[t];
    if (t == 0) offs[0] = 0;
}

__global__ __launch_bounds__(256) void edge_scatter(const int* __restrict__ eidx,
                                                    const int* __restrict__ offs,
                                                    int* __restrict__ cursor,
                                                    int* __restrict__ perm)
{
    const int e = blockIdx.x * 256 + threadIdx.x;
    if (e < NE) {
        const int j = eidx[NE + e];
        const int pos = atomicAdd(&cursor[j], 1);
        perm[offs[j] + pos] = e;
    }
}

// ---------------------------------------------------------------------------
// Kernel: full-feature extraction, bases {12,24}: only TWO gathered A-planes
// per task (was 3 — extract is TA-line-bound, round-12).  12 BT planes in LDS.
//  - k=1..12  : direct LDS reads  bt[b-1][i]   (BT1..BT12)
//  - k=13..24 : MFMA acc0 = P12 rows x bt[nidx], nidx=0..11
//  - k=25..31 : MFMA acc1 = P24 rows x bt[nidx], nidx=0..6
// BT1..8 contiguous at BT18 + b*PLANE; BT9..12 passed as pointers.
// C layout: col=lane&15 (=b), row=(lane>>4)*4+r (=task) [m89-verified].
// ---------------------------------------------------------------------------
__global__ __launch_bounds__(256) void extract_k(const ushort* __restrict__ BT18,
                                                 const ushort* __restrict__ bt9,
                                                 const ushort* __restrict__ bt10,
                                                 const ushort* __restrict__ bt11,
                                                 const ushort* __restrict__ bt12,
                                                 const ushort* __restrict__ A12,
                                                 const ushort* __restrict__ A24,
                                                 const int* __restrict__ eidx,
                                                 const int* __restrict__ perm,
                                                 const int* __restrict__ offs,
                                                 float* __restrict__ out)
{
    const int id = blockIdx.x;
    const int s  = (id & 7) >> 1;
    const int j  = (id >> 3) * 2 + (id & 1);
    const int tid  = threadIdx.x;
    const int wave = tid >> 6;
    const int lane = tid & 63;

    __shared__ __align__(16) ushort bt[12][1032];
    __shared__ int tlist[MAXT];
    __shared__ int elist[MAXT];

    const int base  = offs[j];
    const int cnt   = min(offs[j + 1] - base, MAXT - 1);
    const int ntask = cnt + 1;                   // + diag task
    const int ngrp  = (ntask + 15) >> 4;

    for (int t0 = tid; t0 < MAXT; t0 += 256) {
        int e = -2, i = j;
        if (t0 < cnt)       { e = perm[base + t0]; i = eidx[e]; }
        else if (t0 == cnt) { e = -1; }
        tlist[t0] = i;
        elist[t0] = e;
    }

    // stage 12 BT rows: 2 planes per step (tid<128 -> even b, else odd b)
    const size_t rowbase = ((size_t)s * N + j) * N;
#pragma unroll
    for (int bb = 0; bb < 6; ++bb) {
        const int b0 = 2 * bb, b1 = 2 * bb + 1;
        const ushort* q0 = (b0 < 8) ? (BT18 + (size_t)b0 * PLANE)
                                    : (b0 == 8 ? bt9 : b0 == 9 ? bt10 : b0 == 10 ? bt11 : bt12);
        const ushort* q1 = (b1 < 8) ? (BT18 + (size_t)b1 * PLANE)
                                    : (b1 == 8 ? bt9 : b1 == 9 ? bt10 : b1 == 10 ? bt11 : bt12);
        const ushort* q  = (tid < 128) ? q0 : q1;
        const int b  = b0 + (tid >> 7);
        const int ch = tid & 127;
        const short8 v = *(const short8*)&q[rowbase + ch * 8];
        *(short8*)&bt[b][ch * 8] = v;
    }
    __syncthreads();

    // ---- k = 1..12 straight from LDS ----
    for (int t0 = tid; t0 < ntask; t0 += 256) {
        const int i = tlist[t0];
        const int e = elist[t0];
        const size_t obase = (e >= 0)
            ? ((size_t)N * FEAT + (size_t)e * FEAT + (size_t)s * STEPS)
            : ((size_t)j * FEAT + (size_t)s * STEPS);
#pragma unroll
        for (int b = 0; b < 12; ++b)
            out[obase + b] = bf2f(bt[b][i]);
    }

    // ---- k = 13..31 via MFMA (2 gathered planes) ----
    const int nidx = lane & 15;
    const ushort* bt_ptr = &bt[nidx < 12 ? nidx : 0][(lane >> 4) * 8];

    for (int g = wave; g < ngrp; g += 4) {
        const int i = tlist[g * 16 + nidx];
        const size_t abase = ((size_t)s * N + i) * N + ((lane >> 4) * 8);
        const ushort* pa0 = A12 + abase;
        const ushort* pa1 = A24 + abase;

        f32x4 acc0 = {}, acc1 = {};
#pragma unroll 4
        for (int ks = 0; ks < 32; ++ks) {
            const short8 bf  = *(const short8*)(bt_ptr + ks * 32);
            const short8 af0 = *(const short8*)(pa0 + ks * 32);
            const short8 af1 = *(const short8*)(pa1 + ks * 32);
            acc0 = __builtin_amdgcn_mfma_f32_16x16x32_bf16(af0, bf, acc0, 0, 0, 0);
            acc1 = __builtin_amdgcn_mfma_f32_16x16x32_bf16(af1, bf, acc1, 0, 0, 0);
        }

        if (nidx < 12) {
            const int m0 = (lane >> 4) * 4;
#pragma unroll
            for (int r = 0; r < 4; ++r) {
                const int e = elist[g * 16 + m0 + r];
                if (e >= -1) {
                    const size_t obase = (e >= 0)
                        ? ((size_t)N * FEAT + (size_t)e * FEAT + (size_t)s * STEPS)
                        : ((size_t)j * FEAT + (size_t)s * STEPS);
                    out[obase + 12 + nidx] = acc0[r];          // k = 13..24
                    if (nidx < 7)
                        out[obase + 24 + nidx] = acc1[r];      // k = 25..31
                }
            }
        }
    }
}

// ---------------------------------------------------------------------------
// Plane (slot) liveness map — 15 planes of 8 MB, verified op-by-op:
//  S0 : BT1h (transpose)                       [persist -> extract]
//  S1 : BT2h (P2.CTh)                          [persist]
//  S2 : BT3h (leaf1 P3.CTh)                    [persist]
//  S3 : BT4h (P4.CTh)                          [persist]
//  S4 : BT5h (leaf1 P5.CTh)                    [persist]
//  S5 : BT6h (P6.CTh)                          [persist]
//  S6 : BT7h (leaf1 P7.CTh)                    [persist]
//  S7 : BT8h (P8.CTh)                          [persist]
//  S8 : P1h -> P4l -> P8h (leaf2 A)            [dead after leaf2]
//  S9 : P1l -> P6l -> P24h (P24.Ch)            [persist -> extract]
//  S10: BT1l -> BT11h (leaf2 P11.CTh)          [persist]
//  S11: BT2l -> BT12h (leaf2 P12.CTh)          [persist]
//  S12: P2h -> P12h (leaf2 P12.Ch)             [persist -> extract]
//  S13: P2l -> P6h -> BT9h (leaf2 P9.CTh)      [persist]
//  S14: P4h -> BT10h (leaf2 P10.CTh)           [persist]
// ---------------------------------------------------------------------------
extern "C" void kernel_launch(void* const* d_in, const int* in_sizes, int n_in,
                              void* d_out, int out_size, void* d_ws, size_t ws_size,
                              hipStream_t stream)
{
    const float* coords     = (const float*)d_in[0];
    const float* log_sigmas = (const float*)d_in[1];
    const int*   eidx       = (const int*)d_in[2];
    float*       out        = (float*)d_out;

    ushort* W = (ushort*)d_ws;
    const dim3 tgrid(16, 16, S);
    ushort* const NUL = nullptr;
#define PS(k) (W + (size_t)(k) * PLANE)

    const size_t AUX_INTS = 1024 + 1024 + 1025 + NE;
    const size_t NEED_A   = 15 * PLANE * sizeof(ushort) + AUX_INTS * sizeof(int);

    if (ws_size >= NEED_A) {
        int* hist   = (int*)(W + 15 * PLANE);
        int* cursor = hist + 1024;
        int* offs   = cursor + 1024;
        int* perm   = offs + 1025;

        zero_aux<<<8, 256, 0, stream>>>(hist, 2048);   // hist + cursor
        edge_hist<<<NE / 256, 256, 0, stream>>>(eidx, hist);
        scan1024<<<1, 1024, 0, stream>>>(hist, offs);
        edge_scatter<<<NE / 256, 256, 0, stream>>>(eidx, offs, cursor, perm);

        build_P<<<N, 256, 0, stream>>>(coords, log_sigmas, PS(8), PS(9));
        transpose_hl<<<tgrid, 256, 0, stream>>>(PS(8), PS(9), PS(0), PS(10));

        // P2 = P1*P1 : C split -> S12,S13 ; CT split -> S1(BT2h), S11(BT2l)
        gemm_tile<true><<<256, 512, 0, stream>>>(PS(8), PS(9), PS(0), PS(10),
                                                 PS(12), PS(13), PS(1), PS(11));
        // P4 = P2*P2 : C split -> S14,S8 ; CTh -> S3 (BT4h)
        gemm_tile<true><<<256, 512, 0, stream>>>(PS(12), PS(13), PS(1), PS(11),
                                                 PS(14), PS(8), PS(3), NUL);
        // P6 = P4*P2 : C split -> S13,S9 ; CTh -> S5 (BT6h)
        gemm_tile<true><<<256, 512, 0, stream>>>(PS(14), PS(8), PS(1), PS(11),
                                                 PS(13), PS(9), PS(5), NUL);
        // P8 = P6*P2 : Ch -> S8 ; CTh -> S7 (BT8h)
        gemm_tile<true><<<256, 512, 0, stream>>>(PS(13), PS(9), PS(1), PS(11),
                                                 PS(8), NUL, PS(7), NUL);
        // leaf1 (batched): P3=P2*P1 ->BT3h(S2); P5=P4*P1 ->BT5h(S4); P7=P6*P1 ->BT7h(S6)
        gemm_leaf<<<768, 512, 0, stream>>>(
            PS(12), PS(0), NUL, PS(2),
            PS(14), PS(0), NUL, PS(4),
            PS(13), PS(0), NUL, PS(6),
            NUL, NUL, NUL, NUL);
        // leaf2 (batched): P9=P8*P1 ->BT9h(S13); P10=P8*P2 ->BT10h(S14);
        //                  P11=P8*P3 ->BT11h(S10); P12=P8*P4 ->Ch S12 + BT12h(S11)
        gemm_leaf<<<1024, 512, 0, stream>>>(
            PS(8), PS(0), NUL, PS(13),
            PS(8), PS(1), NUL, PS(14),
            PS(8), PS(2), NUL, PS(10),
            PS(8), PS(3), PS(12), PS(11));
        // P24 = P12*P12 : A = P12h(S12), B = BT12h(S11) -> Ch S9
        gemm_tile<false><<<256, 512, 0, stream>>>(PS(12), NUL, PS(11), NUL,
                                                  PS(9), NUL, NUL, NUL);

        extract_k<<<N * S, 256, 0, stream>>>(PS(0), PS(13), PS(14), PS(10), PS(11),
                                             PS(12), PS(9), eidx, perm, offs, out);
    } else {
        // ---- fallback: linear chain (6 planes = 48 MB) ----
        ushort* ping_h = PS(0); ushort* ping_l = PS(1);
        ushort* pong_h = PS(2); ushort* pong_l = PS(3);
        ushort* bt_h   = PS(4); ushort* bt_l   = PS(5);
        const int gather_blocks = (S * N + S * NE + 255) / 256;

        build_P<<<N, 256, 0, stream>>>(coords, log_sigmas, ping_h, ping_l);
        gather_hl<<<gather_blocks, 256, 0, stream>>>(ping_h, ping_l, eidx, out, 0);
        transpose_hl<<<tgrid, 256, 0, stream>>>(ping_h, ping_l, bt_h, bt_l);

        ushort* cur_h = ping_h; ushort* cur_l = ping_l;
        ushort* nxt_h = pong_h; ushort* nxt_l = pong_l;
        for (int k = 2; k <= STEPS; ++k) {
            gemm_tile<true><<<256, 512, 0, stream>>>(cur_h, cur_l, bt_h, bt_l,
                                                     nxt_h, nxt_l, NUL, NUL);
            gather_hl<<<gather_blocks, 256, 0, stream>>>(nxt_h, nxt_l, eidx, out, k - 1);
            ushort* th = cur_h; ushort* tl = cur_l;
            cur_h = nxt_h; cur_l = nxt_l; nxt_h = th; nxt_l = tl;
        }
    }
#undef PS
}

// Round 17
// 347.126 us; speedup vs baseline: 1.0259x; 1.0259x over previous
//
#include <hip/hip_runtime.h>

#define N 1024
#define NE 32768
#define S 4
#define STEPS 31
#define FEAT (S * STEPS)  // 124
#define PLANE ((size_t)S * N * N)   // 4 Mi elements (8 MB as ushort)
#define MAXT 192

typedef short short8 __attribute__((ext_vector_type(8)));
typedef short short4v __attribute__((ext_vector_type(4)));
typedef float f32x4 __attribute__((ext_vector_type(4)));

// ---- bf16 helpers (RNE) ---------------------------------------------------
__device__ __forceinline__ ushort f2bf(float x) {
    union { float f; unsigned u; } v; v.f = x;
    unsigned r = v.u + 0x7fffu + ((v.u >> 16) & 1u);
    return (ushort)(r >> 16);
}
__device__ __forceinline__ float bf2f(ushort h) {
    union { unsigned u; float f; } v; v.u = ((unsigned)h) << 16;
    return v.f;
}

__device__ __forceinline__ void gload16(const ushort* g, ushort* l) {
    __builtin_amdgcn_global_load_lds(
        (const __attribute__((address_space(1))) unsigned int*)g,
        (__attribute__((address_space(3))) unsigned int*)l, 16, 0, 0);
}

// ---------------------------------------------------------------------------
// Kernel: build P (split bf16 hi/lo), row-major [s][i][j].
// ---------------------------------------------------------------------------
__global__ __launch_bounds__(256) void build_P(const float* __restrict__ coords,
                                               const float* __restrict__ log_sigmas,
                                               ushort* __restrict__ Oh,
                                               ushort* __restrict__ Ol)
{
    const int i   = blockIdx.x;
    const int tid = threadIdx.x;

    float sg[S];
#pragma unroll
    for (int s = 0; s < S; ++s) sg[s] = expf(log_sigmas[s]);
#define CSWP(a, b) { float lo = fminf(sg[a], sg[b]); float hi = fmaxf(sg[a], sg[b]); sg[a] = lo; sg[b] = hi; }
    CSWP(0, 1) CSWP(2, 3) CSWP(0, 2) CSWP(1, 3) CSWP(1, 2)
#undef CSWP
    float inv2s2[S];
#pragma unroll
    for (int s = 0; s < S; ++s) inv2s2[s] = 1.0f / (2.0f * sg[s] * sg[s]);

    const float cx = coords[3 * i + 0];
    const float cy = coords[3 * i + 1];
    const float cz = coords[3 * i + 2];

    float w[4][S];
    float part[S] = {0.f, 0.f, 0.f, 0.f};
#pragma unroll
    for (int c = 0; c < 4; ++c) {
        const int j = tid + c * 256;
        const float dx = cx - coords[3 * j + 0];
        const float dy = cy - coords[3 * j + 1];
        const float dz = cz - coords[3 * j + 2];
        const float d2 = dx * dx + dy * dy + dz * dz;
#pragma unroll
        for (int s = 0; s < S; ++s) {
            const float v = (j == i) ? 0.0f : expf(-d2 * inv2s2[s]);
            w[c][s] = v;
            part[s] += v;
        }
    }

    __shared__ float red[S][256];
#pragma unroll
    for (int s = 0; s < S; ++s) red[s][tid] = part[s];
    __syncthreads();
    for (int st = 128; st > 0; st >>= 1) {
        if (tid < st) {
#pragma unroll
            for (int s = 0; s < S; ++s) red[s][tid] += red[s][tid + st];
        }
        __syncthreads();
    }

    float invden[S];
#pragma unroll
    for (int s = 0; s < S; ++s) invden[s] = 1.0f / fmaxf(red[s][0], 1e-12f);

#pragma unroll
    for (int c = 0; c < 4; ++c) {
        const int j = tid + c * 256;
#pragma unroll
        for (int s = 0; s < S; ++s) {
            const float p = w[c][s] * invden[s];
            const size_t off = ((size_t)s * N + i) * N + j;
            const ushort h = f2bf(p);
            Oh[off] = h;
            Ol[off] = f2bf(p - bf2f(h));
        }
    }
}

// ---------------------------------------------------------------------------
// Kernel: transpose hi/lo pair (used once, for BT1).
// ---------------------------------------------------------------------------
__global__ __launch_bounds__(256) void transpose_hl(const ushort* __restrict__ Xh,
                                                    const ushort* __restrict__ Xl,
                                                    ushort* __restrict__ Yh,
                                                    ushort* __restrict__ Yl)
{
    __shared__ float tile[64][65];
    const size_t zb = (size_t)blockIdx.z * N * N;
    const int tr = blockIdx.y * 64, tc = blockIdx.x * 64;
    const int tid = threadIdx.x;
    const int c  = tid & 63;
    const int r0 = tid >> 6;
#pragma unroll
    for (int i = 0; i < 16; ++i) {
        const int r = r0 + i * 4;
        const size_t idx = zb + (size_t)(tr + r) * N + tc + c;
        tile[r][c] = bf2f(Xh[idx]) + bf2f(Xl[idx]);
    }
    __syncthreads();
#pragma unroll
    for (int i = 0; i < 16; ++i) {
        const int r = r0 + i * 4;
        const size_t idx = zb + (size_t)(tc + r) * N + tr + c;
        const float x = tile[c][r];
        const ushort h = f2bf(x);
        Yh[idx] = h;
        if (Yl) Yl[idx] = f2bf(x - bf2f(h));
    }
}

// ---------------------------------------------------------------------------
// GEMM body (proven round-10..15 schedule): 128x128 tile, BK=32, 8 waves,
// 32x64 wave slice, quad-buffered LDS, depth-2 counted-vmcnt prefetch, one
// barrier per K-step, setprio around MFMA cluster.
// SPLIT=1: C = (Ah+Al)@B, B=(BTh+BTl)^T, 3 MFMA passes.
// SPLIT=0: C = Ah@BTh^T, 1 pass.
// Outputs nullable: Ch/Cl row-major bf16; CTh/CTl transposed bf16.
// ---------------------------------------------------------------------------
template <bool SPLIT>
__device__ __forceinline__ void gemm_body(const ushort* __restrict__ Ah,
                                          const ushort* __restrict__ Al,
                                          const ushort* __restrict__ BTh,
                                          const ushort* __restrict__ BTl,
                                          ushort* __restrict__ Ch,
                                          ushort* __restrict__ Cl,
                                          ushort* __restrict__ CTh,
                                          ushort* __restrict__ CTl,
                                          int id)
{
    constexpr int NP = SPLIT ? 4 : 2;           // LDS parts
    __shared__ ushort smem[4][NP][128 * 32];    // 128 KB (split) / 64 KB
    const int tid  = threadIdx.x;
    const int w    = tid >> 6;                  // wave 0..7
    const int lane = tid & 63;
    const int wr   = w >> 1;                    // wave row-block 0..3
    const int wc   = w & 1;                     // wave col-block 0..1

    const int yrow = id & 7;
    const int rest = id >> 3;
    const int xcol = rest & 7;
    const int z    = rest >> 3;
    const size_t zb = (size_t)z * N * N;
    const int tr = yrow * 128;
    const int tc = xcol * 128;

    const ushort* gA0 = Ah  + zb + (size_t)tr * N;
    const ushort* gA1 = SPLIT ? (Al  + zb + (size_t)tr * N) : nullptr;
    const ushort* gB0 = BTh + zb + (size_t)tc * N;
    const ushort* gB1 = SPLIT ? (BTl + zb + (size_t)tc * N) : nullptr;

    f32x4 acc[2][4] = {};                       // wave's 32x64 slice

    auto STAGE = [&](int bufi, int k0) __attribute__((always_inline)) {
        const int row = tid >> 2;               // 0..127
        const int kg  = (tid & 3) ^ ((row >> 1) & 3);
        const size_t go = (size_t)row * N + k0 + kg * 8;
        const int lb = w * 512;                 // wave-uniform LDS base (elems)
        gload16(gA0 + go, &smem[bufi][0][lb]);
        if constexpr (SPLIT) {
            gload16(gA1 + go, &smem[bufi][1][lb]);
            gload16(gB0 + go, &smem[bufi][2][lb]);
            gload16(gB1 + go, &smem[bufi][3][lb]);
        } else {
            gload16(gB0 + go, &smem[bufi][1][lb]);
        }
    };

    const int lrow = lane & 15;
    const int lkg  = lane >> 4;

    auto COMPUTE = [&](int bufi) __attribute__((always_inline)) {
        short8 ah[2], al[2], bh[4], bl[4];
#pragma unroll
        for (int m = 0; m < 2; ++m) {
            const int arow = wr * 32 + m * 16 + lrow;
            const int aoff = arow * 32 + ((lkg ^ ((arow >> 1) & 3)) << 3);
            ah[m] = *(const short8*)&smem[bufi][0][aoff];
            if constexpr (SPLIT) al[m] = *(const short8*)&smem[bufi][1][aoff];
        }
#pragma unroll
        for (int n = 0; n < 4; ++n) {
            const int brow = wc * 64 + n * 16 + lrow;
            const int boff = brow * 32 + ((lkg ^ ((brow >> 1) & 3)) << 3);
            if constexpr (SPLIT) {
                bh[n] = *(const short8*)&smem[bufi][2][boff];
                bl[n] = *(const short8*)&smem[bufi][3][boff];
            } else {
                bh[n] = *(const short8*)&smem[bufi][1][boff];
            }
        }
        __builtin_amdgcn_s_setprio(1);
#pragma unroll
        for (int m = 0; m < 2; ++m)
#pragma unroll
            for (int n = 0; n < 4; ++n) {
                acc[m][n] = __builtin_amdgcn_mfma_f32_16x16x32_bf16(ah[m], bh[n], acc[m][n], 0, 0, 0);
                if constexpr (SPLIT) {
                    acc[m][n] = __builtin_amdgcn_mfma_f32_16x16x32_bf16(ah[m], bl[n], acc[m][n], 0, 0, 0);
                    acc[m][n] = __builtin_amdgcn_mfma_f32_16x16x32_bf16(al[m], bh[n], acc[m][n], 0, 0, 0);
                }
            }
        __builtin_amdgcn_s_setprio(0);
    };

    STAGE(0, 0);
    STAGE(1, 32);
#pragma unroll 1
    for (int t = 0; t < 32; ++t) {
        __builtin_amdgcn_sched_barrier(0);
        if (t < 30) {
            STAGE((t + 2) & 3, (t + 2) * 32);
            if constexpr (SPLIT) asm volatile("s_waitcnt vmcnt(8)" ::: "memory");
            else                 asm volatile("s_waitcnt vmcnt(4)" ::: "memory");
        } else if (t == 30) {
            if constexpr (SPLIT) asm volatile("s_waitcnt vmcnt(4)" ::: "memory");
            else                 asm volatile("s_waitcnt vmcnt(2)" ::: "memory");
        } else {
            asm volatile("s_waitcnt vmcnt(0)" ::: "memory");
        }
        __builtin_amdgcn_s_barrier();                 // tile t visible to all
        __builtin_amdgcn_sched_barrier(0);
        COMPUTE(t & 3);
        __builtin_amdgcn_sched_barrier(0);
    }

    // epilogue
#pragma unroll
    for (int m = 0; m < 2; ++m)
#pragma unroll
    for (int n = 0; n < 4; ++n) {
        const f32x4 v = acc[m][n];
        ushort hs[4], ls[4];
#pragma unroll
        for (int r = 0; r < 4; ++r) {
            const float x = v[r];
            hs[r] = f2bf(x);
            ls[r] = f2bf(x - bf2f(hs[r]));
        }
        const int row0 = tr + wr * 32 + m * 16 + lkg * 4;
        const int col  = tc + wc * 64 + n * 16 + lrow;
        if (Ch) {
#pragma unroll
            for (int r = 0; r < 4; ++r) {
                const size_t idx = zb + (size_t)(row0 + r) * N + col;
                Ch[idx] = hs[r];
                if (Cl) Cl[idx] = ls[r];
            }
        }
        if (CTh) {
            short4v hv;
            hv[0] = (short)hs[0]; hv[1] = (short)hs[1];
            hv[2] = (short)hs[2]; hv[3] = (short)hs[3];
            *(short4v*)&CTh[zb + (size_t)col * N + row0] = hv;
            if (CTl) {
                short4v lv;
                lv[0] = (short)ls[0]; lv[1] = (short)ls[1];
                lv[2] = (short)ls[2]; lv[3] = (short)ls[3];
                *(short4v*)&CTl[zb + (size_t)col * N + row0] = lv;
            }
        }
    }
}

template <bool SPLIT>
__global__ __launch_bounds__(512) void gemm_tile(const ushort* __restrict__ Ah,
                                                 const ushort* __restrict__ Al,
                                                 const ushort* __restrict__ BTh,
                                                 const ushort* __restrict__ BTl,
                                                 ushort* __restrict__ Ch,
                                                 ushort* __restrict__ Cl,
                                                 ushort* __restrict__ CTh,
                                                 ushort* __restrict__ CTl)
{
    gemm_body<SPLIT>(Ah, Al, BTh, BTl, Ch, Cl, CTh, CTl, blockIdx.x);
}

// Batched hi-only leaf GEMMs: up to 4 independent ops per dispatch.
__global__ __launch_bounds__(512) void gemm_leaf(
    const ushort* A0, const ushort* B0, ushort* C0, ushort* T0,
    const ushort* A1, const ushort* B1, ushort* C1, ushort* T1,
    const ushort* A2, const ushort* B2, ushort* C2, ushort* T2,
    const ushort* A3, const ushort* B3, ushort* C3, ushort* T3)
{
    const int op = blockIdx.x >> 8;
    const int id = blockIdx.x & 255;
    const ushort* A; const ushort* B; ushort* C; ushort* T;
    if      (op == 0) { A = A0; B = B0; C = C0; T = T0; }
    else if (op == 1) { A = A1; B = B1; C = C1; T = T1; }
    else if (op == 2) { A = A2; B = B2; C = C2; T = T2; }
    else              { A = A3; B = B3; C = C3; T = T3; }
    gemm_body<false>(A, nullptr, B, nullptr, C, nullptr, T, nullptr, id);
}

// ---------------------------------------------------------------------------
// Kernel: gather diag + edges (fallback path only).
// ---------------------------------------------------------------------------
__global__ __launch_bounds__(256) void gather_hl(const ushort* __restrict__ Ph,
                                                 const ushort* __restrict__ Pl,
                                                 const int* __restrict__ eidx,
                                                 float* __restrict__ out,
                                                 int t)
{
    const int tid = blockIdx.x * blockDim.x + threadIdx.x;
    const int ND = S * N;
    if (tid < ND) {
        const int s = tid >> 10;
        const int n = tid & (N - 1);
        const size_t off = ((size_t)s * N + n) * N + n;
        float v = bf2f(Ph[off]);
        if (Pl) v += bf2f(Pl[off]);
        out[(size_t)n * FEAT + s * STEPS + t] = v;
    } else {
        const int idx = tid - ND;
        if (idx >= S * NE) return;
        const int s = idx >> 15;
        const int e = idx & (NE - 1);
        const int i = eidx[e];
        const int j = eidx[NE + e];
        const size_t off = ((size_t)s * N + i) * N + j;
        float v = bf2f(Ph[off]);
        if (Pl) v += bf2f(Pl[off]);
        out[(size_t)N * FEAT + (size_t)e * FEAT + s * STEPS + t] = v;
    }
}

// ---------------------------------------------------------------------------
// Bucketing (counting sort of edges by destination column j = eidx[NE+e]).
// ---------------------------------------------------------------------------
__global__ __launch_bounds__(256) void zero_aux(int* __restrict__ p, int n)
{
    for (int i = blockIdx.x * 256 + threadIdx.x; i < n; i += gridDim.x * 256) p[i] = 0;
}

__global__ __launch_bounds__(256) void edge_hist(const int* __restrict__ eidx,
                                                 int* __restrict__ hist)
{
    const int e = blockIdx.x * 256 + threadIdx.x;
    if (e < NE) atomicAdd(&hist[eidx[NE + e]], 1);
}

__global__ __launch_bounds__(1024) void scan1024(const int* __restrict__ hist,
                                                 int* __restrict__ offs)
{
    __shared__ int tmp[1024];
    const int t = threadIdx.x;
    tmp[t] = hist[t];
    __syncthreads();
    for (int d = 1; d < 1024; d <<= 1) {
        int v = (t >= d) ? tmp[t - d] : 0;
        __syncthreads();
        tmp[t] += v;
        __syncthreads();
    }
    offs[t + 1] = tmp[t];
    if (t == 0) offs[0] = 0;
}

__global__ __launch_bounds__(256) void edge_scatter(const int* __restrict__ eidx,
                                                    const int* __restrict__ offs,
                                                    int* __restrict__ cursor,
                                                    int* __restrict__ perm)
{
    const int e = blockIdx.x * 256 + threadIdx.x;
    if (e < NE) {
        const int j = eidx[NE + e];
        const int pos = atomicAdd(&cursor[j], 1);
        perm[offs[j] + pos] = e;
    }
}

// ---------------------------------------------------------------------------
// Kernel: full-feature extraction, bases {12,24}, bf16 gathered planes
// (round-15 proven form: 87us, absmax 0.0117 — fp8 variant REVERTED, its 3%
// mantissa error blew the 2e-2 budget).
//  - k=1..12  : direct LDS reads of BT1..12 (12 contiguous planes)
//  - k=13..24 : MFMA acc0 = A12 rows x bt[nidx], nidx=0..11
//  - k=25..31 : MFMA acc1 = A24 rows x bt[nidx], nidx=0..6
// C layout: col=lane&15 (=b), row=(lane>>4)*4+r (=task) [m89-verified].
// ---------------------------------------------------------------------------
__global__ __launch_bounds__(256) void extract_k(const ushort* __restrict__ BT,   // 12 planes
                                                 const ushort* __restrict__ A12,
                                                 const ushort* __restrict__ A24,
                                                 const int* __restrict__ eidx,
                                                 const int* __restrict__ perm,
                                                 const int* __restrict__ offs,
                                                 float* __restrict__ out)
{
    const int id = blockIdx.x;
    const int s  = (id & 7) >> 1;
    const int j  = (id >> 3) * 2 + (id & 1);
    const int tid  = threadIdx.x;
    const int wave = tid >> 6;
    const int lane = tid & 63;

    __shared__ __align__(16) ushort bt[12][1032];
    __shared__ int tlist[MAXT];
    __shared__ int elist[MAXT];

    const int base  = offs[j];
    const int cnt   = min(offs[j + 1] - base, MAXT - 1);
    const int ntask = cnt + 1;                   // + diag task
    const int ngrp  = (ntask + 15) >> 4;

    for (int t0 = tid; t0 < MAXT; t0 += 256) {
        int e = -2, i = j;
        if (t0 < cnt)       { e = perm[base + t0]; i = eidx[e]; }
        else if (t0 == cnt) { e = -1; }
        tlist[t0] = i;
        elist[t0] = e;
    }

    const size_t rowbase = ((size_t)s * N + j) * N;
    for (int c = tid; c < 12 * 128; c += 256) {
        const int b  = c >> 7;
        const int ch = c & 127;
        const short8 v = *(const short8*)&BT[(size_t)b * PLANE + rowbase + ch * 8];
        *(short8*)&bt[b][ch * 8] = v;
    }
    __syncthreads();

    // ---- k = 1..12 straight from LDS ----
    for (int t0 = tid; t0 < ntask; t0 += 256) {
        const int i = tlist[t0];
        const int e = elist[t0];
        const size_t obase = (e >= 0)
            ? ((size_t)N * FEAT + (size_t)e * FEAT + (size_t)s * STEPS)
            : ((size_t)j * FEAT + (size_t)s * STEPS);
#pragma unroll
        for (int b = 0; b < 12; ++b)
            out[obase + b] = bf2f(bt[b][i]);
    }

    // ---- k = 13..31 via MFMA (2 gathered bf16 planes) ----
    const int nidx = lane & 15;
    const int koff = (lane >> 4) * 8;
    const ushort* bt_ptr = &bt[nidx < 12 ? nidx : 0][koff];

    for (int g = wave; g < ngrp; g += 4) {
        const int i = tlist[g * 16 + nidx];
        const size_t abase = ((size_t)s * N + i) * N + koff;
        const ushort* pa0 = A12 + abase;
        const ushort* pa1 = A24 + abase;

        f32x4 acc0 = {}, acc1 = {};
#pragma unroll 4
        for (int ks = 0; ks < 32; ++ks) {
            const short8 bf  = *(const short8*)(bt_ptr + ks * 32);
            const short8 af0 = *(const short8*)(pa0 + ks * 32);
            const short8 af1 = *(const short8*)(pa1 + ks * 32);
            acc0 = __builtin_amdgcn_mfma_f32_16x16x32_bf16(af0, bf, acc0, 0, 0, 0);
            acc1 = __builtin_amdgcn_mfma_f32_16x16x32_bf16(af1, bf, acc1, 0, 0, 0);
        }

        if (nidx < 12) {
            const int m0 = (lane >> 4) * 4;
#pragma unroll
            for (int r = 0; r < 4; ++r) {
                const int e = elist[g * 16 + m0 + r];
                if (e >= -1) {
                    const size_t obase = (e >= 0)
                        ? ((size_t)N * FEAT + (size_t)e * FEAT + (size_t)s * STEPS)
                        : ((size_t)j * FEAT + (size_t)s * STEPS);
                    out[obase + 12 + nidx] = acc0[r];          // k = 13..24
                    if (nidx < 7)
                        out[obase + 24 + nidx] = acc1[r];      // k = 25..31
                }
            }
        }
    }
}

// ---------------------------------------------------------------------------
// Plane (slot) liveness — 15 slots of 8 MB, checked op-by-op:
//  S0..S11 : BT1h..BT12h (contiguous -> extract)
//  S12 : P1h (op1-3) -> P8h (op6-8)
//  S13 : P1l (op1-3) -> P12h (op8 -> extract A12)
//  S14 : P24h (op9 -> extract A24)
//  S4  : BT1l (op2-3) -> BT5h (leafA)
//  S5  : BT2l (op3-4) -> BT6h (leafA)
//  S6  : P2h  (op3-leafA) -> BT7h (leafB)
//  S8  : P4l  (op4-6) -> BT9h (leafB)
//  S9  : BT4l (op4-6) -> BT10h (leafB)
//  S10 : P2l  (op3-4) -> BT11h (leafB)
//  S11 : P4h  (op4-leafB) -> BT12h (op8)
// Order: P2, P4, leafA{P3,P5,P6}, P8=P4*P4, leafB{P7,P9,P10,P11}, P12, P24.
// (P12 cannot join leafB: its CT target S11 is leafB's live A operand.)
// ---------------------------------------------------------------------------
extern "C" void kernel_launch(void* const* d_in, const int* in_sizes, int n_in,
                              void* d_out, int out_size, void* d_ws, size_t ws_size,
                              hipStream_t stream)
{
    const float* coords     = (const float*)d_in[0];
    const float* log_sigmas = (const float*)d_in[1];
    const int*   eidx       = (const int*)d_in[2];
    float*       out        = (float*)d_out;

    ushort* W = (ushort*)d_ws;
    const dim3 tgrid(16, 16, S);
    ushort* const NUL = nullptr;
#define PS(k) (W + (size_t)(k) * PLANE)

    const size_t AUX_INTS = 1024 + 1024 + 1025 + NE;
    const size_t NEED_A   = 15 * PLANE * sizeof(ushort) + AUX_INTS * sizeof(int);

    if (ws_size >= NEED_A) {
        int* hist   = (int*)(W + 15 * PLANE);
        int* cursor = hist + 1024;
        int* offs   = cursor + 1024;
        int* perm   = offs + 1025;

        zero_aux<<<8, 256, 0, stream>>>(hist, 2048);   // hist + cursor
        edge_hist<<<NE / 256, 256, 0, stream>>>(eidx, hist);
        scan1024<<<1, 1024, 0, stream>>>(hist, offs);
        edge_scatter<<<NE / 256, 256, 0, stream>>>(eidx, offs, cursor, perm);

        build_P<<<N, 256, 0, stream>>>(coords, log_sigmas, PS(12), PS(13));
        transpose_hl<<<tgrid, 256, 0, stream>>>(PS(12), PS(13), PS(0), PS(4));

        // P2 = P1*P1 : Ch->S6, Cl->S10, CTh->S1(BT2h), CTl->S5(BT2l)
        gemm_tile<true><<<256, 512, 0, stream>>>(PS(12), PS(13), PS(0), PS(4),
                                                 PS(6), PS(10), PS(1), PS(5));
        // P4 = P2*P2 : Ch->S11, Cl->S8, CTh->S3(BT4h), CTl->S9(BT4l)
        gemm_tile<true><<<256, 512, 0, stream>>>(PS(6), PS(10), PS(1), PS(5),
                                                 PS(11), PS(8), PS(3), PS(9));
        // leafA: P3=P2h*BT1 ->BT3h(S2); P5=P4h*BT1 ->BT5h(S4); P6=P4h*BT2 ->BT6h(S5)
        gemm_leaf<<<768, 512, 0, stream>>>(
            PS(6), PS(0), NUL, PS(2),
            PS(11), PS(0), NUL, PS(4),
            PS(11), PS(1), NUL, PS(5),
            NUL, NUL, NUL, NUL);
        // P8 = P4*P4 (split in, hi out): Ch->S12(P8h), CTh->S7(BT8h)
        gemm_tile<true><<<256, 512, 0, stream>>>(PS(11), PS(8), PS(3), PS(9),
                                                 PS(12), NUL, PS(7), NUL);
        // leafB: P7=P4h*BT3 ->BT7h(S6); P9=P8h*BT1 ->BT9h(S8);
        //        P10=P8h*BT2 ->BT10h(S9); P11=P8h*BT3 ->BT11h(S10)
        gemm_leaf<<<1024, 512, 0, stream>>>(
            PS(11), PS(2), NUL, PS(6),
            PS(12), PS(0), NUL, PS(8),
            PS(12), PS(1), NUL, PS(9),
            PS(12), PS(2), NUL, PS(10));
        // P12 = P8h*BT4 : Ch->S13(P12h), CTh->S11(BT12h)
        gemm_tile<false><<<256, 512, 0, stream>>>(PS(12), NUL, PS(3), NUL,
                                                  PS(13), NUL, PS(11), NUL);
        // P24 = P12h*BT12 : Ch->S14(P24h)
        gemm_tile<false><<<256, 512, 0, stream>>>(PS(13), NUL, PS(11), NUL,
                                                  PS(14), NUL, NUL, NUL);

        extract_k<<<N * S, 256, 0, stream>>>(W, PS(13), PS(14), eidx, perm, offs, out);
    } else {
        // ---- fallback: linear chain (6 planes = 48 MB) ----
        ushort* ping_h = PS(0); ushort* ping_l = PS(1);
        ushort* pong_h = PS(2); ushort* pong_l = PS(3);
        ushort* bt_h   = PS(4); ushort* bt_l   = PS(5);
        const int gather_blocks = (S * N + S * NE + 255) / 256;

        build_P<<<N, 256, 0, stream>>>(coords, log_sigmas, ping_h, ping_l);
        gather_hl<<<gather_blocks, 256, 0, stream>>>(ping_h, ping_l, eidx, out, 0);
        transpose_hl<<<tgrid, 256, 0, stream>>>(ping_h, ping_l, bt_h, bt_l);

        ushort* cur_h = ping_h; ushort* cur_l = ping_l;
        ushort* nxt_h = pong_h; ushort* nxt_l = pong_l;
        for (int k = 2; k <= STEPS; ++k) {
            gemm_tile<true><<<256, 512, 0, stream>>>(cur_h, cur_l, bt_h, bt_l,
                                                     nxt_h, nxt_l, NUL, NUL);
            gather_hl<<<gather_blocks, 256, 0, stream>>>(nxt_h, nxt_l, eidx, out, k - 1);
            ushort* th = cur_h; ushort* tl = cur_l;
            cur_h = nxt_h; cur_l = nxt_l; nxt_h = th; nxt_l = tl;
        }
    }
#undef PS
}

// Round 18
// 328.253 us; speedup vs baseline: 1.0849x; 1.0575x over previous
//
#include <hip/hip_runtime.h>

#define N 1024
#define NE 32768
#define S 4
#define STEPS 31
#define FEAT (S * STEPS)  // 124
#define PLANE ((size_t)S * N * N)   // 4 Mi elements (8 MB as ushort)
#define MAXT 192

typedef short short8 __attribute__((ext_vector_type(8)));
typedef short short4v __attribute__((ext_vector_type(4)));
typedef float f32x4 __attribute__((ext_vector_type(4)));
typedef int int4v __attribute__((ext_vector_type(4)));

// ---- bf16 helpers (RNE) ---------------------------------------------------
__device__ __forceinline__ ushort f2bf(float x) {
    union { float f; unsigned u; } v; v.f = x;
    unsigned r = v.u + 0x7fffu + ((v.u >> 16) & 1u);
    return (ushort)(r >> 16);
}
__device__ __forceinline__ float bf2f(ushort h) {
    union { unsigned u; float f; } v; v.u = ((unsigned)h) << 16;
    return v.f;
}

__device__ __forceinline__ void gload16(const ushort* g, ushort* l) {
    __builtin_amdgcn_global_load_lds(
        (const __attribute__((address_space(1))) unsigned int*)g,
        (__attribute__((address_space(3))) unsigned int*)l, 16, 0, 0);
}

// ---------------------------------------------------------------------------
// Kernel: build P (split bf16 hi/lo), row-major [s][i][j].
// ---------------------------------------------------------------------------
__global__ __launch_bounds__(256) void build_P(const float* __restrict__ coords,
                                               const float* __restrict__ log_sigmas,
                                               ushort* __restrict__ Oh,
                                               ushort* __restrict__ Ol)
{
    const int i   = blockIdx.x;
    const int tid = threadIdx.x;

    float sg[S];
#pragma unroll
    for (int s = 0; s < S; ++s) sg[s] = expf(log_sigmas[s]);
#define CSWP(a, b) { float lo = fminf(sg[a], sg[b]); float hi = fmaxf(sg[a], sg[b]); sg[a] = lo; sg[b] = hi; }
    CSWP(0, 1) CSWP(2, 3) CSWP(0, 2) CSWP(1, 3) CSWP(1, 2)
#undef CSWP
    float inv2s2[S];
#pragma unroll
    for (int s = 0; s < S; ++s) inv2s2[s] = 1.0f / (2.0f * sg[s] * sg[s]);

    const float cx = coords[3 * i + 0];
    const float cy = coords[3 * i + 1];
    const float cz = coords[3 * i + 2];

    float w[4][S];
    float part[S] = {0.f, 0.f, 0.f, 0.f};
#pragma unroll
    for (int c = 0; c < 4; ++c) {
        const int j = tid + c * 256;
        const float dx = cx - coords[3 * j + 0];
        const float dy = cy - coords[3 * j + 1];
        const float dz = cz - coords[3 * j + 2];
        const float d2 = dx * dx + dy * dy + dz * dz;
#pragma unroll
        for (int s = 0; s < S; ++s) {
            const float v = (j == i) ? 0.0f : expf(-d2 * inv2s2[s]);
            w[c][s] = v;
            part[s] += v;
        }
    }

    __shared__ float red[S][256];
#pragma unroll
    for (int s = 0; s < S; ++s) red[s][tid] = part[s];
    __syncthreads();
    for (int st = 128; st > 0; st >>= 1) {
        if (tid < st) {
#pragma unroll
            for (int s = 0; s < S; ++s) red[s][tid] += red[s][tid + st];
        }
        __syncthreads();
    }

    float invden[S];
#pragma unroll
    for (int s = 0; s < S; ++s) invden[s] = 1.0f / fmaxf(red[s][0], 1e-12f);

#pragma unroll
    for (int c = 0; c < 4; ++c) {
        const int j = tid + c * 256;
#pragma unroll
        for (int s = 0; s < S; ++s) {
            const float p = w[c][s] * invden[s];
            const size_t off = ((size_t)s * N + i) * N + j;
            const ushort h = f2bf(p);
            Oh[off] = h;
            Ol[off] = f2bf(p - bf2f(h));
        }
    }
}

// ---------------------------------------------------------------------------
// Kernel: transpose hi/lo pair (used once, for BT1).
// ---------------------------------------------------------------------------
__global__ __launch_bounds__(256) void transpose_hl(const ushort* __restrict__ Xh,
                                                    const ushort* __restrict__ Xl,
                                                    ushort* __restrict__ Yh,
                                                    ushort* __restrict__ Yl)
{
    __shared__ float tile[64][65];
    const size_t zb = (size_t)blockIdx.z * N * N;
    const int tr = blockIdx.y * 64, tc = blockIdx.x * 64;
    const int tid = threadIdx.x;
    const int c  = tid & 63;
    const int r0 = tid >> 6;
#pragma unroll
    for (int i = 0; i < 16; ++i) {
        const int r = r0 + i * 4;
        const size_t idx = zb + (size_t)(tr + r) * N + tc + c;
        tile[r][c] = bf2f(Xh[idx]) + bf2f(Xl[idx]);
    }
    __syncthreads();
#pragma unroll
    for (int i = 0; i < 16; ++i) {
        const int r = r0 + i * 4;
        const size_t idx = zb + (size_t)(tc + r) * N + tr + c;
        const float x = tile[c][r];
        const ushort h = f2bf(x);
        Yh[idx] = h;
        if (Yl) Yl[idx] = f2bf(x - bf2f(h));
    }
}

// ---------------------------------------------------------------------------
// GEMM body (proven round-10..17 schedule): 128x128 tile, BK=32, 8 waves,
// 32x64 wave slice, quad-buffered LDS, depth-2 counted-vmcnt prefetch, one
// barrier per K-step, setprio around MFMA cluster.
// SPLIT=1: C = (Ah+Al)@B, B=(BTh+BTl)^T, 3 MFMA passes.
// SPLIT=0: C = Ah@BTh^T, 1 pass.
// Outputs nullable: Ch/Cl row-major bf16; CTh/CTl transposed bf16.
// ---------------------------------------------------------------------------
template <bool SPLIT>
__device__ __forceinline__ void gemm_body(const ushort* __restrict__ Ah,
                                          const ushort* __restrict__ Al,
                                          const ushort* __restrict__ BTh,
                                          const ushort* __restrict__ BTl,
                                          ushort* __restrict__ Ch,
                                          ushort* __restrict__ Cl,
                                          ushort* __restrict__ CTh,
                                          ushort* __restrict__ CTl,
                                          int id)
{
    constexpr int NP = SPLIT ? 4 : 2;           // LDS parts
    __shared__ ushort smem[4][NP][128 * 32];    // 128 KB (split) / 64 KB
    const int tid  = threadIdx.x;
    const int w    = tid >> 6;                  // wave 0..7
    const int lane = tid & 63;
    const int wr   = w >> 1;                    // wave row-block 0..3
    const int wc   = w & 1;                     // wave col-block 0..1

    const int yrow = id & 7;
    const int rest = id >> 3;
    const int xcol = rest & 7;
    const int z    = rest >> 3;
    const size_t zb = (size_t)z * N * N;
    const int tr = yrow * 128;
    const int tc = xcol * 128;

    const ushort* gA0 = Ah  + zb + (size_t)tr * N;
    const ushort* gA1 = SPLIT ? (Al  + zb + (size_t)tr * N) : nullptr;
    const ushort* gB0 = BTh + zb + (size_t)tc * N;
    const ushort* gB1 = SPLIT ? (BTl + zb + (size_t)tc * N) : nullptr;

    f32x4 acc[2][4] = {};                       // wave's 32x64 slice

    auto STAGE = [&](int bufi, int k0) __attribute__((always_inline)) {
        const int row = tid >> 2;               // 0..127
        const int kg  = (tid & 3) ^ ((row >> 1) & 3);
        const size_t go = (size_t)row * N + k0 + kg * 8;
        const int lb = w * 512;                 // wave-uniform LDS base (elems)
        gload16(gA0 + go, &smem[bufi][0][lb]);
        if constexpr (SPLIT) {
            gload16(gA1 + go, &smem[bufi][1][lb]);
            gload16(gB0 + go, &smem[bufi][2][lb]);
            gload16(gB1 + go, &smem[bufi][3][lb]);
        } else {
            gload16(gB0 + go, &smem[bufi][1][lb]);
        }
    };

    const int lrow = lane & 15;
    const int lkg  = lane >> 4;

    auto COMPUTE = [&](int bufi) __attribute__((always_inline)) {
        short8 ah[2], al[2], bh[4], bl[4];
#pragma unroll
        for (int m = 0; m < 2; ++m) {
            const int arow = wr * 32 + m * 16 + lrow;
            const int aoff = arow * 32 + ((lkg ^ ((arow >> 1) & 3)) << 3);
            ah[m] = *(const short8*)&smem[bufi][0][aoff];
            if constexpr (SPLIT) al[m] = *(const short8*)&smem[bufi][1][aoff];
        }
#pragma unroll
        for (int n = 0; n < 4; ++n) {
            const int brow = wc * 64 + n * 16 + lrow;
            const int boff = brow * 32 + ((lkg ^ ((brow >> 1) & 3)) << 3);
            if constexpr (SPLIT) {
                bh[n] = *(const short8*)&smem[bufi][2][boff];
                bl[n] = *(const short8*)&smem[bufi][3][boff];
            } else {
                bh[n] = *(const short8*)&smem[bufi][1][boff];
            }
        }
        __builtin_amdgcn_s_setprio(1);
#pragma unroll
        for (int m = 0; m < 2; ++m)
#pragma unroll
            for (int n = 0; n < 4; ++n) {
                acc[m][n] = __builtin_amdgcn_mfma_f32_16x16x32_bf16(ah[m], bh[n], acc[m][n], 0, 0, 0);
                if constexpr (SPLIT) {
                    acc[m][n] = __builtin_amdgcn_mfma_f32_16x16x32_bf16(ah[m], bl[n], acc[m][n], 0, 0, 0);
                    acc[m][n] = __builtin_amdgcn_mfma_f32_16x16x32_bf16(al[m], bh[n], acc[m][n], 0, 0, 0);
                }
            }
        __builtin_amdgcn_s_setprio(0);
    };

    STAGE(0, 0);
    STAGE(1, 32);
#pragma unroll 1
    for (int t = 0; t < 32; ++t) {
        __builtin_amdgcn_sched_barrier(0);
        if (t < 30) {
            STAGE((t + 2) & 3, (t + 2) * 32);
            if constexpr (SPLIT) asm volatile("s_waitcnt vmcnt(8)" ::: "memory");
            else                 asm volatile("s_waitcnt vmcnt(4)" ::: "memory");
        } else if (t == 30) {
            if constexpr (SPLIT) asm volatile("s_waitcnt vmcnt(4)" ::: "memory");
            else                 asm volatile("s_waitcnt vmcnt(2)" ::: "memory");
        } else {
            asm volatile("s_waitcnt vmcnt(0)" ::: "memory");
        }
        __builtin_amdgcn_s_barrier();                 // tile t visible to all
        __builtin_amdgcn_sched_barrier(0);
        COMPUTE(t & 3);
        __builtin_amdgcn_sched_barrier(0);
    }

    // epilogue
#pragma unroll
    for (int m = 0; m < 2; ++m)
#pragma unroll
    for (int n = 0; n < 4; ++n) {
        const f32x4 v = acc[m][n];
        ushort hs[4], ls[4];
#pragma unroll
        for (int r = 0; r < 4; ++r) {
            const float x = v[r];
            hs[r] = f2bf(x);
            ls[r] = f2bf(x - bf2f(hs[r]));
        }
        const int row0 = tr + wr * 32 + m * 16 + lkg * 4;
        const int col  = tc + wc * 64 + n * 16 + lrow;
        if (Ch) {
#pragma unroll
            for (int r = 0; r < 4; ++r) {
                const size_t idx = zb + (size_t)(row0 + r) * N + col;
                Ch[idx] = hs[r];
                if (Cl) Cl[idx] = ls[r];
            }
        }
        if (CTh) {
            short4v hv;
            hv[0] = (short)hs[0]; hv[1] = (short)hs[1];
            hv[2] = (short)hs[2]; hv[3] = (short)hs[3];
            *(short4v*)&CTh[zb + (size_t)col * N + row0] = hv;
            if (CTl) {
                short4v lv;
                lv[0] = (short)ls[0]; lv[1] = (short)ls[1];
                lv[2] = (short)ls[2]; lv[3] = (short)ls[3];
                *(short4v*)&CTl[zb + (size_t)col * N + row0] = lv;
            }
        }
    }
}

template <bool SPLIT>
__global__ __launch_bounds__(512) void gemm_tile(const ushort* __restrict__ Ah,
                                                 const ushort* __restrict__ Al,
                                                 const ushort* __restrict__ BTh,
                                                 const ushort* __restrict__ BTl,
                                                 ushort* __restrict__ Ch,
                                                 ushort* __restrict__ Cl,
                                                 ushort* __restrict__ CTh,
                                                 ushort* __restrict__ CTl)
{
    gemm_body<SPLIT>(Ah, Al, BTh, BTl, Ch, Cl, CTh, CTl, blockIdx.x);
}

// Batched hi-only leaf GEMMs: up to 5 independent ops per dispatch.
__global__ __launch_bounds__(512) void gemm_leaf(
    const ushort* A0, const ushort* B0, ushort* C0, ushort* T0,
    const ushort* A1, const ushort* B1, ushort* C1, ushort* T1,
    const ushort* A2, const ushort* B2, ushort* C2, ushort* T2,
    const ushort* A3, const ushort* B3, ushort* C3, ushort* T3,
    const ushort* A4, const ushort* B4, ushort* C4, ushort* T4)
{
    const int op = blockIdx.x >> 8;
    const int id = blockIdx.x & 255;
    const ushort* A; const ushort* B; ushort* C; ushort* T;
    if      (op == 0) { A = A0; B = B0; C = C0; T = T0; }
    else if (op == 1) { A = A1; B = B1; C = C1; T = T1; }
    else if (op == 2) { A = A2; B = B2; C = C2; T = T2; }
    else if (op == 3) { A = A3; B = B3; C = C3; T = T3; }
    else              { A = A4; B = B4; C = C4; T = T4; }
    gemm_body<false>(A, nullptr, B, nullptr, C, nullptr, T, nullptr, id);
}

// ---------------------------------------------------------------------------
// Kernel: quantize bf16 plane rows -> int8 (per-row scale).  Row id covers
// both planes: id<4096 -> P12h, else P24h.  sc[id] = rowmax/127 so that
// value ~= q * sc.  Rows are >0 (stochastic powers); guard vs 0 anyway.
// ---------------------------------------------------------------------------
__global__ __launch_bounds__(128) void quant8(const ushort* __restrict__ X12,
                                              const ushort* __restrict__ X24,
                                              unsigned char* __restrict__ Q,
                                              float* __restrict__ sc)
{
    const int id  = blockIdx.x;            // 0..8191
    const int pl  = id >> 12;              // 0: P12, 1: P24
    const int row = id & 4095;
    const int tid = threadIdx.x;
    const ushort* src = (pl ? X24 : X12) + (size_t)row * N;
    unsigned char* dst = Q + (size_t)pl * PLANE + (size_t)row * N;

    float v[8];
    const short8 x = ((const short8*)src)[tid];
    float mx = 0.0f;
#pragma unroll
    for (int e = 0; e < 8; ++e) { v[e] = bf2f((ushort)x[e]); mx = fmaxf(mx, v[e]); }
#pragma unroll
    for (int d = 1; d < 64; d <<= 1) mx = fmaxf(mx, __shfl_xor(mx, d, 64));
    __shared__ float wmx[2];
    if ((tid & 63) == 0) wmx[tid >> 6] = mx;
    __syncthreads();
    mx = fmaxf(fmaxf(wmx[0], wmx[1]), 1e-30f);

    const float inv = 127.0f / mx;
    uint2 q;
    q.x = 0; q.y = 0;
#pragma unroll
    for (int e = 0; e < 4; ++e) {
        q.x |= ((unsigned)(int)(v[e] * inv + 0.5f)) << (e * 8);
        q.y |= ((unsigned)(int)(v[4 + e] * inv + 0.5f)) << (e * 8);
    }
    ((uint2*)dst)[tid] = q;
    if (tid == 0) sc[id] = mx * (1.0f / 127.0f);
}

// ---------------------------------------------------------------------------
// Kernel: gather diag + edges (fallback path only).
// ---------------------------------------------------------------------------
__global__ __launch_bounds__(256) void gather_hl(const ushort* __restrict__ Ph,
                                                 const ushort* __restrict__ Pl,
                                                 const int* __restrict__ eidx,
                                                 float* __restrict__ out,
                                                 int t)
{
    const int tid = blockIdx.x * blockDim.x + threadIdx.x;
    const int ND = S * N;
    if (tid < ND) {
        const int s = tid >> 10;
        const int n = tid & (N - 1);
        const size_t off = ((size_t)s * N + n) * N + n;
        float v = bf2f(Ph[off]);
        if (Pl) v += bf2f(Pl[off]);
        out[(size_t)n * FEAT + s * STEPS + t] = v;
    } else {
        const int idx = tid - ND;
        if (idx >= S * NE) return;
        const int s = idx >> 15;
        const int e = idx & (NE - 1);
        const int i = eidx[e];
        const int j = eidx[NE + e];
        const size_t off = ((size_t)s * N + i) * N + j;
        float v = bf2f(Ph[off]);
        if (Pl) v += bf2f(Pl[off]);
        out[(size_t)N * FEAT + (size_t)e * FEAT + s * STEPS + t] = v;
    }
}

// ---------------------------------------------------------------------------
// Bucketing (counting sort of edges by destination column j = eidx[NE+e]).
// ---------------------------------------------------------------------------
__global__ __launch_bounds__(256) void zero_aux(int* __restrict__ p, int n)
{
    for (int i = blockIdx.x * 256 + threadIdx.x; i < n; i += gridDim.x * 256) p[i] = 0;
}

__global__ __launch_bounds__(256) void edge_hist(const int* __restrict__ eidx,
                                                 int* __restrict__ hist)
{
    const int e = blockIdx.x * 256 + threadIdx.x;
    if (e < NE) atomicAdd(&hist[eidx[NE + e]], 1);
}

__global__ __launch_bounds__(1024) void scan1024(const int* __restrict__ hist,
                                                 int* __restrict__ offs)
{
    __shared__ int tmp[1024];
    const int t = threadIdx.x;
    tmp[t] = hist[t];
    __syncthreads();
    for (int d = 1; d < 1024; d <<= 1) {
        int v = (t >= d) ? tmp[t - d] : 0;
        __syncthreads();
        tmp[t] += v;
        __syncthreads();
    }
    offs[t + 1] = tmp[t];
    if (t == 0) offs[0] = 0;
}

__global__ __launch_bounds__(256) void edge_scatter(const int* __restrict__ eidx,
                                                    const int* __restrict__ offs,
                                                    int* __restrict__ cursor,
                                                    int* __restrict__ perm)
{
    const int e = blockIdx.x * 256 + threadIdx.x;
    if (e < NE) {
        const int j = eidx[NE + e];
        const int pos = atomicAdd(&cursor[j], 1);
        perm[offs[j] + pos] = e;
    }
}

// ---------------------------------------------------------------------------
// Kernel: full-feature extraction, bases {12,24}, INT8 gathered planes
// (halves the TA-line traffic that bounds this kernel — rounds 12/15/17).
//  - k=1..12  : direct LDS reads of BT1..12 (bf16)
//  - k=13..24 : i8-MFMA acc0 = A12q rows x btq[nidx], nidx=0..11
//  - k=25..31 : i8-MFMA acc1 = A24q rows x btq[nidx], nidx=0..6
// Dequant: val = acc_int * scA(row) * scB(btrow); scA from quant8, scB
// computed in-kernel from the staged bf16 rows (per-row max / 127).
// A/B use identical lane->k addressing so the HW k-permutation cancels.
// C layout: col=lane&15 (=b), row=(lane>>4)*4+r (=task) [m89-verified].
// ---------------------------------------------------------------------------
__global__ __launch_bounds__(256) void extract_k(const ushort* __restrict__ BT18,
                                                 const ushort* __restrict__ bt9p,
                                                 const ushort* __restrict__ bt10p,
                                                 const ushort* __restrict__ bt11p,
                                                 const ushort* __restrict__ bt12p,
                                                 const unsigned char* __restrict__ Q,
                                                 const float* __restrict__ sc,
                                                 const int* __restrict__ eidx,
                                                 const int* __restrict__ perm,
                                                 const int* __restrict__ offs,
                                                 float* __restrict__ out)
{
    const int id = blockIdx.x;
    const int s  = (id & 7) >> 1;
    const int j  = (id >> 3) * 2 + (id & 1);
    const int tid  = threadIdx.x;
    const int wave = tid >> 6;
    const int lane = tid & 63;

    __shared__ __align__(16) ushort bt[12][1032];
    __shared__ __align__(16) unsigned char btq[12][1040];
    __shared__ int tlist[MAXT];
    __shared__ int elist[MAXT];
    __shared__ float saA[MAXT], saC[MAXT];
    __shared__ int   rowmaxi[12];
    __shared__ float sbq[12], sbinv[12];

    if (tid < 12) rowmaxi[tid] = 0;
    __syncthreads();

    const int base  = offs[j];
    const int cnt   = min(offs[j + 1] - base, MAXT - 1);
    const int ntask = cnt + 1;                   // + diag task
    const int ngrp  = (ntask + 15) >> 4;

    for (int t0 = tid; t0 < MAXT; t0 += 256) {
        int e = -2, i = j;
        if (t0 < cnt)       { e = perm[base + t0]; i = eidx[e]; }
        else if (t0 == cnt) { e = -1; }
        tlist[t0] = i;
        elist[t0] = e;
    }

    const size_t rowbase = ((size_t)s * N + j) * N;
    for (int c = tid; c < 12 * 128; c += 256) {
        const int b  = c >> 7;
        const int ch = c & 127;
        const ushort* q = (b < 8) ? (BT18 + (size_t)b * PLANE)
                        : (b == 8 ? bt9p : b == 9 ? bt10p : b == 10 ? bt11p : bt12p);
        const short8 v = *(const short8*)&q[rowbase + ch * 8];
        *(short8*)&bt[b][ch * 8] = v;
        float mx = 0.0f;
#pragma unroll
        for (int x = 0; x < 8; ++x) mx = fmaxf(mx, bf2f((ushort)v[x]));
        atomicMax(&rowmaxi[b], __float_as_int(mx));
    }
    __syncthreads();

    if (tid < 12) {
        const float rm = fmaxf(__int_as_float(rowmaxi[tid]), 1e-30f);
        sbq[tid]   = rm * (1.0f / 127.0f);
        sbinv[tid] = 127.0f / rm;
    }
    __syncthreads();

    // quantize B rows; stage per-task A scales; direct k=1..12 writes
    for (int c = tid; c < 12 * 128; c += 256) {
        const int b  = c >> 7;
        const int ch = c & 127;
        const float inv = sbinv[b];
        uint2 q; q.x = 0; q.y = 0;
#pragma unroll
        for (int x = 0; x < 4; ++x) {
            q.x |= ((unsigned)(int)(bf2f(bt[b][ch * 8 + x]) * inv + 0.5f)) << (x * 8);
            q.y |= ((unsigned)(int)(bf2f(bt[b][ch * 8 + 4 + x]) * inv + 0.5f)) << (x * 8);
        }
        *(uint2*)&btq[b][ch * 8] = q;
    }
    for (int t0 = tid; t0 < MAXT; t0 += 256) {
        const int i = tlist[t0];
        saA[t0] = sc[s * N + i];
        saC[t0] = sc[S * N + s * N + i];
    }
    for (int t0 = tid; t0 < ntask; t0 += 256) {
        const int i = tlist[t0];
        const int e = elist[t0];
        const size_t obase = (e >= 0)
            ? ((size_t)N * FEAT + (size_t)e * FEAT + (size_t)s * STEPS)
            : ((size_t)j * FEAT + (size_t)s * STEPS);
#pragma unroll
        for (int b = 0; b < 12; ++b)
            out[obase + b] = bf2f(bt[b][i]);
    }
    __syncthreads();

    // ---- k = 13..31 via int8 MFMA (K=64, 16 iters) ----
    const int nidx = lane & 15;
    const int koff = (lane >> 4) * 16;           // BYTE offset within row
    const unsigned char* btq_ptr = &btq[nidx < 12 ? nidx : 0][koff];

    for (int g = wave; g < ngrp; g += 4) {
        const int i = tlist[g * 16 + nidx];
        const size_t abase = ((size_t)s * N + i) * N + koff;   // bytes
        const unsigned char* pa0 = Q + abase;
        const unsigned char* pa1 = Q + PLANE + abase;

        int4v acc0 = {}, acc1 = {};
#pragma unroll 8
        for (int ks = 0; ks < 16; ++ks) {
            const int4v bv  = *(const int4v*)(btq_ptr + ks * 64);
            const int4v av0 = *(const int4v*)(pa0 + ks * 64);
            const int4v av1 = *(const int4v*)(pa1 + ks * 64);
            acc0 = __builtin_amdgcn_mfma_i32_16x16x64_i8(av0, bv, acc0, 0, 0, 0);
            acc1 = __builtin_amdgcn_mfma_i32_16x16x64_i8(av1, bv, acc1, 0, 0, 0);
        }

        if (nidx < 12) {
            const int m0 = (lane >> 4) * 4;
            const float sb = sbq[nidx];
#pragma unroll
            for (int r = 0; r < 4; ++r) {
                const int task = g * 16 + m0 + r;
                const int e = elist[task];
                if (e >= -1) {
                    const size_t obase = (e >= 0)
                        ? ((size_t)N * FEAT + (size_t)e * FEAT + (size_t)s * STEPS)
                        : ((size_t)j * FEAT + (size_t)s * STEPS);
                    out[obase + 12 + nidx] = (float)acc0[r] * saA[task] * sb;
                    if (nidx < 7)
                        out[obase + 24 + nidx] = (float)acc1[r] * saC[task] * sb;
                }
            }
        }
    }
}

// ---------------------------------------------------------------------------
// Plane (slot) liveness — 15 slots of 8 MB, checked op-by-op:
//  op1 build      -> S12(P1h) S13(P1l)
//  op2 transpose  : R S12,S13 -> W S0(BT1h) S8(BT1l)
//  op3 P2 split   : R S12,S13,S0,S8 -> W S9(P2h) S10(P2l) S1(BT2h) S11(BT2l)
//  op4 P4 split   : R S9,S10,S1,S11 -> W S12(P4h) S13(P4l) S3(BT4h) S14(BT4l)
//  leafA          : R S9,S12,S0,S1 -> W S2(BT3h) S4(BT5h) S5(BT6h)
//  op6 P8 split   : R S12,S13,S3,S14 -> W S9(P8h) S7(BT8h)
//  leafB (5 ops)  : R S12,S2,S9,S0,S1,S3 ->
//                   W S6(BT7h) S10(BT9h) S11(BT10h) S13(BT11h)
//                     S14(P12h) S8(BT12h)          [reads/writes disjoint]
//  op8 P24        : R S14,S8 -> W S12(P24h)
//  op9 quant8     : R S14,S12 -> W S9-as-int8 (A12q|A24q), sc (aux)
//  extract        : BT1..8 = S0..S7, bt9..12 = S10,S11,S13,S8; Q=S9; sc aux
// ---------------------------------------------------------------------------
extern "C" void kernel_launch(void* const* d_in, const int* in_sizes, int n_in,
                              void* d_out, int out_size, void* d_ws, size_t ws_size,
                              hipStream_t stream)
{
    const float* coords     = (const float*)d_in[0];
    const float* log_sigmas = (const float*)d_in[1];
    const int*   eidx       = (const int*)d_in[2];
    float*       out        = (float*)d_out;

    ushort* W = (ushort*)d_ws;
    const dim3 tgrid(16, 16, S);
    ushort* const NUL = nullptr;
#define PS(k) (W + (size_t)(k) * PLANE)

    const size_t AUX_INTS = 1024 + 1024 + 1025 + NE + 2 * S * N;  // + scales
    const size_t NEED_A   = 15 * PLANE * sizeof(ushort) + AUX_INTS * sizeof(int);

    if (ws_size >= NEED_A) {
        int* hist   = (int*)(W + 15 * PLANE);
        int* cursor = hist + 1024;
        int* offs   = cursor + 1024;
        int* perm   = offs + 1025;
        float* sc   = (float*)(perm + NE);

        zero_aux<<<8, 256, 0, stream>>>(hist, 2048);   // hist + cursor
        edge_hist<<<NE / 256, 256, 0, stream>>>(eidx, hist);
        scan1024<<<1, 1024, 0, stream>>>(hist, offs);
        edge_scatter<<<NE / 256, 256, 0, stream>>>(eidx, offs, cursor, perm);

        build_P<<<N, 256, 0, stream>>>(coords, log_sigmas, PS(12), PS(13));
        transpose_hl<<<tgrid, 256, 0, stream>>>(PS(12), PS(13), PS(0), PS(8));

        // P2 = P1*P1
        gemm_tile<true><<<256, 512, 0, stream>>>(PS(12), PS(13), PS(0), PS(8),
                                                 PS(9), PS(10), PS(1), PS(11));
        // P4 = P2*P2
        gemm_tile<true><<<256, 512, 0, stream>>>(PS(9), PS(10), PS(1), PS(11),
                                                 PS(12), PS(13), PS(3), PS(14));
        // leafA: P3=P2h*BT1 ->BT3h(S2); P5=P4h*BT1 ->BT5h(S4); P6=P4h*BT2 ->BT6h(S5)
        gemm_leaf<<<768, 512, 0, stream>>>(
            PS(9), PS(0), NUL, PS(2),
            PS(12), PS(0), NUL, PS(4),
            PS(12), PS(1), NUL, PS(5),
            NUL, NUL, NUL, NUL,
            NUL, NUL, NUL, NUL);
        // P8 = P4*P4 (split in, hi out): Ch->S9(P8h), CTh->S7(BT8h)
        gemm_tile<true><<<256, 512, 0, stream>>>(PS(12), PS(13), PS(3), PS(14),
                                                 PS(9), NUL, PS(7), NUL);
        // leafB (5): P7=P4h*BT3 ->BT7h(S6); P9=P8h*BT1 ->BT9h(S10);
        //            P10=P8h*BT2 ->BT10h(S11); P11=P8h*BT3 ->BT11h(S13);
        //            P12=P8h*BT4 ->Ch S14(P12h) + CT S8(BT12h)
        gemm_leaf<<<1280, 512, 0, stream>>>(
            PS(12), PS(2), NUL, PS(6),
            PS(9), PS(0), NUL, PS(10),
            PS(9), PS(1), NUL, PS(11),
            PS(9), PS(2), NUL, PS(13),
            PS(9), PS(3), PS(14), PS(8));
        // P24 = P12h*BT12 : Ch->S12(P24h)
        gemm_tile<false><<<256, 512, 0, stream>>>(PS(14), NUL, PS(8), NUL,
                                                  PS(12), NUL, NUL, NUL);
        // quantize P12h/P24h -> int8 planes in S9 + scales
        quant8<<<2 * S * N, 128, 0, stream>>>(PS(14), PS(12),
                                              (unsigned char*)PS(9), sc);

        extract_k<<<N * S, 256, 0, stream>>>(W, PS(10), PS(11), PS(13), PS(8),
                                             (const unsigned char*)PS(9), sc,
                                             eidx, perm, offs, out);
    } else {
        // ---- fallback: linear chain (6 planes = 48 MB) ----
        ushort* ping_h = PS(0); ushort* ping_l = PS(1);
        ushort* pong_h = PS(2); ushort* pong_l = PS(3);
        ushort* bt_h   = PS(4); ushort* bt_l   = PS(5);
        const int gather_blocks = (S * N + S * NE + 255) / 256;

        build_P<<<N, 256, 0, stream>>>(coords, log_sigmas, ping_h, ping_l);
        gather_hl<<<gather_blocks, 256, 0, stream>>>(ping_h, ping_l, eidx, out, 0);
        transpose_hl<<<tgrid, 256, 0, stream>>>(ping_h, ping_l, bt_h, bt_l);

        ushort* cur_h = ping_h; ushort* cur_l = ping_l;
        ushort* nxt_h = pong_h; ushort* nxt_l = pong_l;
        for (int k = 2; k <= STEPS; ++k) {
            gemm_tile<true><<<256, 512, 0, stream>>>(cur_h, cur_l, bt_h, bt_l,
                                                     nxt_h, nxt_l, NUL, NUL);
            gather_hl<<<gather_blocks, 256, 0, stream>>>(nxt_h, nxt_l, eidx, out, k - 1);
            ushort* th = cur_h; ushort* tl = cur_l;
            cur_h = nxt_h; cur_l = nxt_l; nxt_h = th; nxt_l = tl;
        }
    }
#undef PS
}

// Round 19
// 301.060 us; speedup vs baseline: 1.1829x; 1.0903x over previous
//
#include <hip/hip_runtime.h>

#define N 1024
#define NE 32768
#define S 4
#define STEPS 31
#define FEAT (S * STEPS)  // 124
#define PLANE ((size_t)S * N * N)   // 4 Mi elements (8 MB as ushort)
#define MAXT 192

typedef short short8 __attribute__((ext_vector_type(8)));
typedef short short4v __attribute__((ext_vector_type(4)));
typedef float f32x4 __attribute__((ext_vector_type(4)));
typedef int int4v __attribute__((ext_vector_type(4)));

// ---- bf16 helpers (RNE) ---------------------------------------------------
__device__ __forceinline__ ushort f2bf(float x) {
    union { float f; unsigned u; } v; v.f = x;
    unsigned r = v.u + 0x7fffu + ((v.u >> 16) & 1u);
    return (ushort)(r >> 16);
}
__device__ __forceinline__ float bf2f(ushort h) {
    union { unsigned u; float f; } v; v.u = ((unsigned)h) << 16;
    return v.f;
}

__device__ __forceinline__ void gload16(const ushort* g, ushort* l) {
    __builtin_amdgcn_global_load_lds(
        (const __attribute__((address_space(1))) unsigned int*)g,
        (__attribute__((address_space(3))) unsigned int*)l, 16, 0, 0);
}

// ---------------------------------------------------------------------------
// Kernel: build P (split bf16 hi/lo), row-major [s][i][j].
// ---------------------------------------------------------------------------
__global__ __launch_bounds__(256) void build_P(const float* __restrict__ coords,
                                               const float* __restrict__ log_sigmas,
                                               ushort* __restrict__ Oh,
                                               ushort* __restrict__ Ol)
{
    const int i   = blockIdx.x;
    const int tid = threadIdx.x;

    float sg[S];
#pragma unroll
    for (int s = 0; s < S; ++s) sg[s] = expf(log_sigmas[s]);
#define CSWP(a, b) { float lo = fminf(sg[a], sg[b]); float hi = fmaxf(sg[a], sg[b]); sg[a] = lo; sg[b] = hi; }
    CSWP(0, 1) CSWP(2, 3) CSWP(0, 2) CSWP(1, 3) CSWP(1, 2)
#undef CSWP
    float inv2s2[S];
#pragma unroll
    for (int s = 0; s < S; ++s) inv2s2[s] = 1.0f / (2.0f * sg[s] * sg[s]);

    const float cx = coords[3 * i + 0];
    const float cy = coords[3 * i + 1];
    const float cz = coords[3 * i + 2];

    float w[4][S];
    float part[S] = {0.f, 0.f, 0.f, 0.f};
#pragma unroll
    for (int c = 0; c < 4; ++c) {
        const int j = tid + c * 256;
        const float dx = cx - coords[3 * j + 0];
        const float dy = cy - coords[3 * j + 1];
        const float dz = cz - coords[3 * j + 2];
        const float d2 = dx * dx + dy * dy + dz * dz;
#pragma unroll
        for (int s = 0; s < S; ++s) {
            const float v = (j == i) ? 0.0f : expf(-d2 * inv2s2[s]);
            w[c][s] = v;
            part[s] += v;
        }
    }

    __shared__ float red[S][256];
#pragma unroll
    for (int s = 0; s < S; ++s) red[s][tid] = part[s];
    __syncthreads();
    for (int st = 128; st > 0; st >>= 1) {
        if (tid < st) {
#pragma unroll
            for (int s = 0; s < S; ++s) red[s][tid] += red[s][tid + st];
        }
        __syncthreads();
    }

    float invden[S];
#pragma unroll
    for (int s = 0; s < S; ++s) invden[s] = 1.0f / fmaxf(red[s][0], 1e-12f);

#pragma unroll
    for (int c = 0; c < 4; ++c) {
        const int j = tid + c * 256;
#pragma unroll
        for (int s = 0; s < S; ++s) {
            const float p = w[c][s] * invden[s];
            const size_t off = ((size_t)s * N + i) * N + j;
            const ushort h = f2bf(p);
            Oh[off] = h;
            Ol[off] = f2bf(p - bf2f(h));
        }
    }
}

// ---------------------------------------------------------------------------
// Kernel: transpose hi/lo pair (used once, for BT1).
// ---------------------------------------------------------------------------
__global__ __launch_bounds__(256) void transpose_hl(const ushort* __restrict__ Xh,
                                                    const ushort* __restrict__ Xl,
                                                    ushort* __restrict__ Yh,
                                                    ushort* __restrict__ Yl)
{
    __shared__ float tile[64][65];
    const size_t zb = (size_t)blockIdx.z * N * N;
    const int tr = blockIdx.y * 64, tc = blockIdx.x * 64;
    const int tid = threadIdx.x;
    const int c  = tid & 63;
    const int r0 = tid >> 6;
#pragma unroll
    for (int i = 0; i < 16; ++i) {
        const int r = r0 + i * 4;
        const size_t idx = zb + (size_t)(tr + r) * N + tc + c;
        tile[r][c] = bf2f(Xh[idx]) + bf2f(Xl[idx]);
    }
    __syncthreads();
#pragma unroll
    for (int i = 0; i < 16; ++i) {
        const int r = r0 + i * 4;
        const size_t idx = zb + (size_t)(tc + r) * N + tr + c;
        const float x = tile[c][r];
        const ushort h = f2bf(x);
        Yh[idx] = h;
        if (Yl) Yl[idx] = f2bf(x - bf2f(h));
    }
}

// ---------------------------------------------------------------------------
// GEMM body (proven round-10..18 schedule): 128x128 tile, BK=32, 8 waves,
// 32x64 wave slice, quad-buffered LDS, depth-2 counted-vmcnt prefetch, one
// barrier per K-step, setprio around MFMA cluster.
// SPLIT=1: C = (Ah+Al)@B, B=(BTh+BTl)^T, 3 MFMA passes.
// SPLIT=0: C = Ah@BTh^T, 1 pass.
// Outputs nullable: Ch/Cl row-major bf16; CTh/CTl transposed bf16.
// ---------------------------------------------------------------------------
template <bool SPLIT>
__device__ __forceinline__ void gemm_body(const ushort* __restrict__ Ah,
                                          const ushort* __restrict__ Al,
                                          const ushort* __restrict__ BTh,
                                          const ushort* __restrict__ BTl,
                                          ushort* __restrict__ Ch,
                                          ushort* __restrict__ Cl,
                                          ushort* __restrict__ CTh,
                                          ushort* __restrict__ CTl,
                                          int id)
{
    constexpr int NP = SPLIT ? 4 : 2;           // LDS parts
    __shared__ ushort smem[4][NP][128 * 32];    // 128 KB (split) / 64 KB
    const int tid  = threadIdx.x;
    const int w    = tid >> 6;                  // wave 0..7
    const int lane = tid & 63;
    const int wr   = w >> 1;                    // wave row-block 0..3
    const int wc   = w & 1;                     // wave col-block 0..1

    const int yrow = id & 7;
    const int rest = id >> 3;
    const int xcol = rest & 7;
    const int z    = rest >> 3;
    const size_t zb = (size_t)z * N * N;
    const int tr = yrow * 128;
    const int tc = xcol * 128;

    const ushort* gA0 = Ah  + zb + (size_t)tr * N;
    const ushort* gA1 = SPLIT ? (Al  + zb + (size_t)tr * N) : nullptr;
    const ushort* gB0 = BTh + zb + (size_t)tc * N;
    const ushort* gB1 = SPLIT ? (BTl + zb + (size_t)tc * N) : nullptr;

    f32x4 acc[2][4] = {};                       // wave's 32x64 slice

    auto STAGE = [&](int bufi, int k0) __attribute__((always_inline)) {
        const int row = tid >> 2;               // 0..127
        const int kg  = (tid & 3) ^ ((row >> 1) & 3);
        const size_t go = (size_t)row * N + k0 + kg * 8;
        const int lb = w * 512;                 // wave-uniform LDS base (elems)
        gload16(gA0 + go, &smem[bufi][0][lb]);
        if constexpr (SPLIT) {
            gload16(gA1 + go, &smem[bufi][1][lb]);
            gload16(gB0 + go, &smem[bufi][2][lb]);
            gload16(gB1 + go, &smem[bufi][3][lb]);
        } else {
            gload16(gB0 + go, &smem[bufi][1][lb]);
        }
    };

    const int lrow = lane & 15;
    const int lkg  = lane >> 4;

    auto COMPUTE = [&](int bufi) __attribute__((always_inline)) {
        short8 ah[2], al[2], bh[4], bl[4];
#pragma unroll
        for (int m = 0; m < 2; ++m) {
            const int arow = wr * 32 + m * 16 + lrow;
            const int aoff = arow * 32 + ((lkg ^ ((arow >> 1) & 3)) << 3);
            ah[m] = *(const short8*)&smem[bufi][0][aoff];
            if constexpr (SPLIT) al[m] = *(const short8*)&smem[bufi][1][aoff];
        }
#pragma unroll
        for (int n = 0; n < 4; ++n) {
            const int brow = wc * 64 + n * 16 + lrow;
            const int boff = brow * 32 + ((lkg ^ ((brow >> 1) & 3)) << 3);
            if constexpr (SPLIT) {
                bh[n] = *(const short8*)&smem[bufi][2][boff];
                bl[n] = *(const short8*)&smem[bufi][3][boff];
            } else {
                bh[n] = *(const short8*)&smem[bufi][1][boff];
            }
        }
        __builtin_amdgcn_s_setprio(1);
#pragma unroll
        for (int m = 0; m < 2; ++m)
#pragma unroll
            for (int n = 0; n < 4; ++n) {
                acc[m][n] = __builtin_amdgcn_mfma_f32_16x16x32_bf16(ah[m], bh[n], acc[m][n], 0, 0, 0);
                if constexpr (SPLIT) {
                    acc[m][n] = __builtin_amdgcn_mfma_f32_16x16x32_bf16(ah[m], bl[n], acc[m][n], 0, 0, 0);
                    acc[m][n] = __builtin_amdgcn_mfma_f32_16x16x32_bf16(al[m], bh[n], acc[m][n], 0, 0, 0);
                }
            }
        __builtin_amdgcn_s_setprio(0);
    };

    STAGE(0, 0);
    STAGE(1, 32);
#pragma unroll 1
    for (int t = 0; t < 32; ++t) {
        __builtin_amdgcn_sched_barrier(0);
        if (t < 30) {
            STAGE((t + 2) & 3, (t + 2) * 32);
            if constexpr (SPLIT) asm volatile("s_waitcnt vmcnt(8)" ::: "memory");
            else                 asm volatile("s_waitcnt vmcnt(4)" ::: "memory");
        } else if (t == 30) {
            if constexpr (SPLIT) asm volatile("s_waitcnt vmcnt(4)" ::: "memory");
            else                 asm volatile("s_waitcnt vmcnt(2)" ::: "memory");
        } else {
            asm volatile("s_waitcnt vmcnt(0)" ::: "memory");
        }
        __builtin_amdgcn_s_barrier();                 // tile t visible to all
        __builtin_amdgcn_sched_barrier(0);
        COMPUTE(t & 3);
        __builtin_amdgcn_sched_barrier(0);
    }

    // epilogue
#pragma unroll
    for (int m = 0; m < 2; ++m)
#pragma unroll
    for (int n = 0; n < 4; ++n) {
        const f32x4 v = acc[m][n];
        ushort hs[4], ls[4];
#pragma unroll
        for (int r = 0; r < 4; ++r) {
            const float x = v[r];
            hs[r] = f2bf(x);
            ls[r] = f2bf(x - bf2f(hs[r]));
        }
        const int row0 = tr + wr * 32 + m * 16 + lkg * 4;
        const int col  = tc + wc * 64 + n * 16 + lrow;
        if (Ch) {
#pragma unroll
            for (int r = 0; r < 4; ++r) {
                const size_t idx = zb + (size_t)(row0 + r) * N + col;
                Ch[idx] = hs[r];
                if (Cl) Cl[idx] = ls[r];
            }
        }
        if (CTh) {
            short4v hv;
            hv[0] = (short)hs[0]; hv[1] = (short)hs[1];
            hv[2] = (short)hs[2]; hv[3] = (short)hs[3];
            *(short4v*)&CTh[zb + (size_t)col * N + row0] = hv;
            if (CTl) {
                short4v lv;
                lv[0] = (short)ls[0]; lv[1] = (short)ls[1];
                lv[2] = (short)ls[2]; lv[3] = (short)ls[3];
                *(short4v*)&CTl[zb + (size_t)col * N + row0] = lv;
            }
        }
    }
}

template <bool SPLIT>
__global__ __launch_bounds__(512) void gemm_tile(const ushort* __restrict__ Ah,
                                                 const ushort* __restrict__ Al,
                                                 const ushort* __restrict__ BTh,
                                                 const ushort* __restrict__ BTl,
                                                 ushort* __restrict__ Ch,
                                                 ushort* __restrict__ Cl,
                                                 ushort* __restrict__ CTh,
                                                 ushort* __restrict__ CTl)
{
    gemm_body<SPLIT>(Ah, Al, BTh, BTl, Ch, Cl, CTh, CTl, blockIdx.x);
}

// Batched hi-only leaf GEMMs: up to 3 independent ops per dispatch.
__global__ __launch_bounds__(512) void gemm_leaf(
    const ushort* A0, const ushort* B0, ushort* C0, ushort* T0,
    const ushort* A1, const ushort* B1, ushort* C1, ushort* T1,
    const ushort* A2, const ushort* B2, ushort* C2, ushort* T2)
{
    const int op = blockIdx.x >> 8;
    const int id = blockIdx.x & 255;
    const ushort* A; const ushort* B; ushort* C; ushort* T;
    if      (op == 0) { A = A0; B = B0; C = C0; T = T0; }
    else if (op == 1) { A = A1; B = B1; C = C1; T = T1; }
    else              { A = A2; B = B2; C = C2; T = T2; }
    gemm_body<false>(A, nullptr, B, nullptr, C, nullptr, T, nullptr, id);
}

// ---------------------------------------------------------------------------
// Kernel: quantize 3 bf16 planes -> int8 (per-row scale).  id selects
// (plane, row): pl = id>>12 (0:P8, 1:P16, 2:P24), row = id&4095.
// sc[id] = rowmax/127 so value ~= q * sc.
// ---------------------------------------------------------------------------
__global__ __launch_bounds__(128) void quant8(const ushort* __restrict__ X0,
                                              const ushort* __restrict__ X1,
                                              const ushort* __restrict__ X2,
                                              unsigned char* __restrict__ Q,
                                              float* __restrict__ sc)
{
    const int id  = blockIdx.x;            // 0..12287
    const int pl  = id >> 12;
    const int row = id & 4095;
    const int tid = threadIdx.x;
    const ushort* src = (pl == 0 ? X0 : pl == 1 ? X1 : X2) + (size_t)row * N;
    unsigned char* dst = Q + (size_t)pl * PLANE + (size_t)row * N;   // PLANE bytes/plane

    float v[8];
    const short8 x = ((const short8*)src)[tid];
    float mx = 0.0f;
#pragma unroll
    for (int e = 0; e < 8; ++e) { v[e] = bf2f((ushort)x[e]); mx = fmaxf(mx, v[e]); }
#pragma unroll
    for (int d = 1; d < 64; d <<= 1) mx = fmaxf(mx, __shfl_xor(mx, d, 64));
    __shared__ float wmx[2];
    if ((tid & 63) == 0) wmx[tid >> 6] = mx;
    __syncthreads();
    mx = fmaxf(fmaxf(wmx[0], wmx[1]), 1e-30f);

    const float inv = 127.0f / mx;
    uint2 q;
    q.x = 0; q.y = 0;
#pragma unroll
    for (int e = 0; e < 4; ++e) {
        q.x |= ((unsigned)(int)(v[e] * inv + 0.5f)) << (e * 8);
        q.y |= ((unsigned)(int)(v[4 + e] * inv + 0.5f)) << (e * 8);
    }
    ((uint2*)dst)[tid] = q;
    if (tid == 0) sc[id] = mx * (1.0f / 127.0f);
}

// ---------------------------------------------------------------------------
// Kernel: gather diag + edges (fallback path only).
// ---------------------------------------------------------------------------
__global__ __launch_bounds__(256) void gather_hl(const ushort* __restrict__ Ph,
                                                 const ushort* __restrict__ Pl,
                                                 const int* __restrict__ eidx,
                                                 float* __restrict__ out,
                                                 int t)
{
    const int tid = blockIdx.x * blockDim.x + threadIdx.x;
    const int ND = S * N;
    if (tid < ND) {
        const int s = tid >> 10;
        const int n = tid & (N - 1);
        const size_t off = ((size_t)s * N + n) * N + n;
        float v = bf2f(Ph[off]);
        if (Pl) v += bf2f(Pl[off]);
        out[(size_t)n * FEAT + s * STEPS + t] = v;
    } else {
        const int idx = tid - ND;
        if (idx >= S * NE) return;
        const int s = idx >> 15;
        const int e = idx & (NE - 1);
        const int i = eidx[e];
        const int j = eidx[NE + e];
        const size_t off = ((size_t)s * N + i) * N + j;
        float v = bf2f(Ph[off]);
        if (Pl) v += bf2f(Pl[off]);
        out[(size_t)N * FEAT + (size_t)e * FEAT + s * STEPS + t] = v;
    }
}

// ---------------------------------------------------------------------------
// Bucketing (counting sort of edges by destination column j = eidx[NE+e]).
// ---------------------------------------------------------------------------
__global__ __launch_bounds__(256) void zero_aux(int* __restrict__ p, int n)
{
    for (int i = blockIdx.x * 256 + threadIdx.x; i < n; i += gridDim.x * 256) p[i] = 0;
}

__global__ __launch_bounds__(256) void edge_hist(const int* __restrict__ eidx,
                                                 int* __restrict__ hist)
{
    const int e = blockIdx.x * 256 + threadIdx.x;
    if (e < NE) atomicAdd(&hist[eidx[NE + e]], 1);
}

__global__ __launch_bounds__(1024) void scan1024(const int* __restrict__ hist,
                                                 int* __restrict__ offs)
{
    __shared__ int tmp[1024];
    const int t = threadIdx.x;
    tmp[t] = hist[t];
    __syncthreads();
    for (int d = 1; d < 1024; d <<= 1) {
        int v = (t >= d) ? tmp[t - d] : 0;
        __syncthreads();
        tmp[t] += v;
        __syncthreads();
    }
    offs[t + 1] = tmp[t];
    if (t == 0) offs[0] = 0;
}

__global__ __launch_bounds__(256) void edge_scatter(const int* __restrict__ eidx,
                                                    const int* __restrict__ offs,
                                                    int* __restrict__ cursor,
                                                    int* __restrict__ perm)
{
    const int e = blockIdx.x * 256 + threadIdx.x;
    if (e < NE) {
        const int j = eidx[NE + e];
        const int pos = atomicAdd(&cursor[j], 1);
        perm[offs[j] + pos] = e;
    }
}

// ---------------------------------------------------------------------------
// Kernel: full-feature extraction, bases {8,16,24}, 3 INT8 gathered planes.
// (int8 halved per-plane gather cost, so 3 planes + 8 BT beats 2 planes +
//  12 BT: kills 4 leaf GEMMs from the chain — rounds 15/18 measurements.)
//  - k=1..8   : direct LDS reads of BT1..8 (bf16)
//  - k=9..16  : i8-MFMA acc0 = P8q rows x btq[nidx], nidx=0..7
//  - k=17..24 : i8-MFMA acc1 = P16q rows x btq[nidx], nidx=0..7
//  - k=25..31 : i8-MFMA acc2 = P24q rows x btq[nidx], nidx=0..6
// Dequant: val = acc_int * scA(plane,row) * scB(btrow).
// A/B use identical lane->k addressing so the HW k-permutation cancels.
// C layout: col=lane&15 (=b), row=(lane>>4)*4+r (=task) [m89-verified].
// ---------------------------------------------------------------------------
__global__ __launch_bounds__(256) void extract_k(const ushort* __restrict__ BT18,
                                                 const unsigned char* __restrict__ Q,
                                                 const float* __restrict__ sc,
                                                 const int* __restrict__ eidx,
                                                 const int* __restrict__ perm,
                                                 const int* __restrict__ offs,
                                                 float* __restrict__ out)
{
    const int id = blockIdx.x;
    const int s  = (id & 7) >> 1;
    const int j  = (id >> 3) * 2 + (id & 1);
    const int tid  = threadIdx.x;
    const int wave = tid >> 6;
    const int lane = tid & 63;

    __shared__ __align__(16) ushort bt[8][1032];
    __shared__ __align__(16) unsigned char btq[8][1040];
    __shared__ int tlist[MAXT];
    __shared__ int elist[MAXT];
    __shared__ float saA[MAXT], saB[MAXT], saC[MAXT];
    __shared__ int   rowmaxi[8];
    __shared__ float sbq[8], sbinv[8];

    if (tid < 8) rowmaxi[tid] = 0;
    __syncthreads();

    const int base  = offs[j];
    const int cnt   = min(offs[j + 1] - base, MAXT - 1);
    const int ntask = cnt + 1;                   // + diag task
    const int ngrp  = (ntask + 15) >> 4;

    for (int t0 = tid; t0 < MAXT; t0 += 256) {
        int e = -2, i = j;
        if (t0 < cnt)       { e = perm[base + t0]; i = eidx[e]; }
        else if (t0 == cnt) { e = -1; }
        tlist[t0] = i;
        elist[t0] = e;
    }

    const size_t rowbase = ((size_t)s * N + j) * N;
    for (int c = tid; c < 8 * 128; c += 256) {
        const int b  = c >> 7;
        const int ch = c & 127;
        const short8 v = *(const short8*)&BT18[(size_t)b * PLANE + rowbase + ch * 8];
        *(short8*)&bt[b][ch * 8] = v;
        float mx = 0.0f;
#pragma unroll
        for (int x = 0; x < 8; ++x) mx = fmaxf(mx, bf2f((ushort)v[x]));
        atomicMax(&rowmaxi[b], __float_as_int(mx));
    }
    __syncthreads();

    if (tid < 8) {
        const float rm = fmaxf(__int_as_float(rowmaxi[tid]), 1e-30f);
        sbq[tid]   = rm * (1.0f / 127.0f);
        sbinv[tid] = 127.0f / rm;
    }
    __syncthreads();

    // quantize B rows; stage per-task A scales; direct k=1..8 writes
    for (int c = tid; c < 8 * 128; c += 256) {
        const int b  = c >> 7;
        const int ch = c & 127;
        const float inv = sbinv[b];
        uint2 q; q.x = 0; q.y = 0;
#pragma unroll
        for (int x = 0; x < 4; ++x) {
            q.x |= ((unsigned)(int)(bf2f(bt[b][ch * 8 + x]) * inv + 0.5f)) << (x * 8);
            q.y |= ((unsigned)(int)(bf2f(bt[b][ch * 8 + 4 + x]) * inv + 0.5f)) << (x * 8);
        }
        *(uint2*)&btq[b][ch * 8] = q;
    }
    for (int t0 = tid; t0 < MAXT; t0 += 256) {
        const int i = tlist[t0];
        saA[t0] = sc[0 * S * N + s * N + i];
        saB[t0] = sc[1 * S * N + s * N + i];
        saC[t0] = sc[2 * S * N + s * N + i];
    }
    for (int t0 = tid; t0 < ntask; t0 += 256) {
        const int i = tlist[t0];
        const int e = elist[t0];
        const size_t obase = (e >= 0)
            ? ((size_t)N * FEAT + (size_t)e * FEAT + (size_t)s * STEPS)
            : ((size_t)j * FEAT + (size_t)s * STEPS);
#pragma unroll
        for (int b = 0; b < 8; ++b)
            out[obase + b] = bf2f(bt[b][i]);
    }
    __syncthreads();

    // ---- k = 9..31 via int8 MFMA (K=64, 16 iters, 3 planes) ----
    const int nidx = lane & 15;
    const int koff = (lane >> 4) * 16;           // BYTE offset within row
    const unsigned char* btq_ptr = &btq[nidx & 7][koff];

    for (int g = wave; g < ngrp; g += 4) {
        const int i = tlist[g * 16 + nidx];
        const size_t abase = ((size_t)s * N + i) * N + koff;   // bytes
        const unsigned char* pa0 = Q + abase;
        const unsigned char* pa1 = Q + PLANE + abase;
        const unsigned char* pa2 = Q + 2 * PLANE + abase;

        int4v acc0 = {}, acc1 = {}, acc2 = {};
#pragma unroll 4
        for (int ks = 0; ks < 16; ++ks) {
            const int4v bv  = *(const int4v*)(btq_ptr + ks * 64);
            const int4v av0 = *(const int4v*)(pa0 + ks * 64);
            const int4v av1 = *(const int4v*)(pa1 + ks * 64);
            const int4v av2 = *(const int4v*)(pa2 + ks * 64);
            acc0 = __builtin_amdgcn_mfma_i32_16x16x64_i8(av0, bv, acc0, 0, 0, 0);
            acc1 = __builtin_amdgcn_mfma_i32_16x16x64_i8(av1, bv, acc1, 0, 0, 0);
            acc2 = __builtin_amdgcn_mfma_i32_16x16x64_i8(av2, bv, acc2, 0, 0, 0);
        }

        if (nidx < 8) {
            const int m0 = (lane >> 4) * 4;
            const float sb = sbq[nidx];
#pragma unroll
            for (int r = 0; r < 4; ++r) {
                const int task = g * 16 + m0 + r;
                const int e = elist[task];
                if (e >= -1) {
                    const size_t obase = (e >= 0)
                        ? ((size_t)N * FEAT + (size_t)e * FEAT + (size_t)s * STEPS)
                        : ((size_t)j * FEAT + (size_t)s * STEPS);
                    out[obase + 8  + nidx] = (float)acc0[r] * saA[task] * sb;  // k=9..16
                    out[obase + 16 + nidx] = (float)acc1[r] * saB[task] * sb;  // k=17..24
                    if (nidx < 7)
                        out[obase + 24 + nidx] = (float)acc2[r] * saC[task] * sb; // k=25..31
                }
            }
        }
    }
}

// ---------------------------------------------------------------------------
// Plane (slot) liveness — 15 slots of 8 MB, checked op-by-op:
//  op1 build      -> W S10(P1h) S11(P1l)
//  op2 transpose  : R S10,S11 -> W S0(BT1h) S12(BT1l)
//  op3 P2 split   : R S10,S11,S0,S12 -> W S13(P2h) S14(P2l) S1(BT2h) S9(BT2l)
//  op4 P4 split   : R S13,S14,S1,S9 -> W S10(P4h) S11(P4l) S3(BT4h) S12(BT4l)
//  leafA (3)      : R S13,S10,S0,S1 -> W S2(BT3h) S4(BT5h) S5(BT6h)
//  op6 P8 split   : R S10,S11,S3,S12 -> W S13(P8h) S7(BT8h)
//  batch2 (2)     : R S10,S2,S13,S7 -> W S6(BT7h) S14(P16h)   [disjoint]
//  op8 P24        : R S14,S7 -> W S10(P24h)
//  op9 quant8     : R S13(P8h),S14(P16h),S10(P24h) -> W Q = S8..S9h (12MB)
//  extract        : R BT1..8 = S0..S7, Q, sc
// ---------------------------------------------------------------------------
extern "C" void kernel_launch(void* const* d_in, const int* in_sizes, int n_in,
                              void* d_out, int out_size, void* d_ws, size_t ws_size,
                              hipStream_t stream)
{
    const float* coords     = (const float*)d_in[0];
    const float* log_sigmas = (const float*)d_in[1];
    const int*   eidx       = (const int*)d_in[2];
    float*       out        = (float*)d_out;

    ushort* W = (ushort*)d_ws;
    const dim3 tgrid(16, 16, S);
    ushort* const NUL = nullptr;
#define PS(k) (W + (size_t)(k) * PLANE)

    const size_t AUX_INTS = 1024 + 1024 + 1025 + NE + 3 * S * N;  // + scales
    const size_t NEED_A   = 15 * PLANE * sizeof(ushort) + AUX_INTS * sizeof(int);

    if (ws_size >= NEED_A) {
        int* hist   = (int*)(W + 15 * PLANE);
        int* cursor = hist + 1024;
        int* offs   = cursor + 1024;
        int* perm   = offs + 1025;
        float* sc   = (float*)(perm + NE);

        unsigned char* Q = (unsigned char*)PS(8);    // 3 int8 planes = 12 MB (S8..S9h)

        zero_aux<<<8, 256, 0, stream>>>(hist, 2048);   // hist + cursor
        edge_hist<<<NE / 256, 256, 0, stream>>>(eidx, hist);
        scan1024<<<1, 1024, 0, stream>>>(hist, offs);
        edge_scatter<<<NE / 256, 256, 0, stream>>>(eidx, offs, cursor, perm);

        build_P<<<N, 256, 0, stream>>>(coords, log_sigmas, PS(10), PS(11));
        transpose_hl<<<tgrid, 256, 0, stream>>>(PS(10), PS(11), PS(0), PS(12));

        // P2 = P1*P1 : Ch->S13, Cl->S14, CTh->S1(BT2h), CTl->S9(BT2l)
        gemm_tile<true><<<256, 512, 0, stream>>>(PS(10), PS(11), PS(0), PS(12),
                                                 PS(13), PS(14), PS(1), PS(9));
        // P4 = P2*P2 : Ch->S10, Cl->S11, CTh->S3(BT4h), CTl->S12(BT4l)
        gemm_tile<true><<<256, 512, 0, stream>>>(PS(13), PS(14), PS(1), PS(9),
                                                 PS(10), PS(11), PS(3), PS(12));
        // leafA: P3=P2h*BT1 ->BT3h(S2); P5=P4h*BT1 ->BT5h(S4); P6=P4h*BT2 ->BT6h(S5)
        gemm_leaf<<<768, 512, 0, stream>>>(
            PS(13), PS(0), NUL, PS(2),
            PS(10), PS(0), NUL, PS(4),
            PS(10), PS(1), NUL, PS(5));
        // P8 = P4*P4 (split in, hi out): Ch->S13(P8h), CTh->S7(BT8h)
        gemm_tile<true><<<256, 512, 0, stream>>>(PS(10), PS(11), PS(3), PS(12),
                                                 PS(13), NUL, PS(7), NUL);
        // batch2: P7=P4h*BT3 ->BT7h(S6); P16=P8h*BT8 ->Ch S14(P16h)
        gemm_leaf<<<512, 512, 0, stream>>>(
            PS(10), PS(2), NUL, PS(6),
            PS(13), PS(7), PS(14), NUL,
            NUL, NUL, NUL, NUL);
        // P24 = P16h*BT8 : Ch->S10(P24h)
        gemm_tile<false><<<256, 512, 0, stream>>>(PS(14), NUL, PS(7), NUL,
                                                  PS(10), NUL, NUL, NUL);
        // quantize P8h/P16h/P24h -> 3 int8 planes + scales
        quant8<<<3 * S * N, 128, 0, stream>>>(PS(13), PS(14), PS(10), Q, sc);

        extract_k<<<N * S, 256, 0, stream>>>(W, Q, sc, eidx, perm, offs, out);
    } else {
        // ---- fallback: linear chain (6 planes = 48 MB) ----
        ushort* ping_h = PS(0); ushort* ping_l = PS(1);
        ushort* pong_h = PS(2); ushort* pong_l = PS(3);
        ushort* bt_h   = PS(4); ushort* bt_l   = PS(5);
        const int gather_blocks = (S * N + S * NE + 255) / 256;

        build_P<<<N, 256, 0, stream>>>(coords, log_sigmas, ping_h, ping_l);
        gather_hl<<<gather_blocks, 256, 0, stream>>>(ping_h, ping_l, eidx, out, 0);
        transpose_hl<<<tgrid, 256, 0, stream>>>(ping_h, ping_l, bt_h, bt_l);

        ushort* cur_h = ping_h; ushort* cur_l = ping_l;
        ushort* nxt_h = pong_h; ushort* nxt_l = pong_l;
        for (int k = 2; k <= STEPS; ++k) {
            gemm_tile<true><<<256, 512, 0, stream>>>(cur_h, cur_l, bt_h, bt_l,
                                                     nxt_h, nxt_l, NUL, NUL);
            gather_hl<<<gather_blocks, 256, 0, stream>>>(nxt_h, nxt_l, eidx, out, k - 1);
            ushort* th = cur_h; ushort* tl = cur_l;
            cur_h = nxt_h; cur_l = nxt_l; nxt_h = th; nxt_l = tl;
        }
    }
#undef PS
}